// Round 19
// baseline (295.182 us; speedup 1.0000x reference)
//
#include <hip/hip_runtime.h>
#include <hip/hip_bf16.h>
#include <stdint.h>

#define S_LEN 2048
#define HDIM  1024
#define NHEAD 16
#define NKVH  4
#define HEADD 64
#define QKV_O 1536   // NKV*(q_per_kv+2)*HD = 4*6*64
#define NEXP  8
#define TOPK  2
#define CAP   640    // ceil(2048*2/8*1.25)
#define TCAP  (NEXP*CAP)
#define FDIM  2048
#define LOG2E 1.44269504088896f
#define NCHUNK 40
#define ATTN_BLOCKS (NCHUNK*NHEAD)   // 640
#define CONV_BLOCKS 8192             // (w1+w2 = 32M f32) / 4096 per block
// interleave: attn at bid%13==6 (bid/13<640). max attn bid = 13*639+6 = 8313
// < 8832 total. conv cv = bid - min(640,(bid+6)/13): bid=8831 -> 8191 (max). ✓

typedef __bf16 bf16x8 __attribute__((ext_vector_type(8)));
typedef float  f32x4  __attribute__((ext_vector_type(4)));
typedef unsigned int u32;
typedef u32 u32x4 __attribute__((ext_vector_type(4)));
typedef u32 u32x2 __attribute__((ext_vector_type(2)));
typedef unsigned short u16;
typedef u16 u16x8 __attribute__((ext_vector_type(8)));

// async global->LDS, 16B per lane
__device__ __forceinline__ void gload16(const __bf16* g, __bf16* l) {
    __builtin_amdgcn_global_load_lds(
        (const __attribute__((address_space(1))) u32*)g,
        (__attribute__((address_space(3))) u32*)l, 16, 0, 0);
}

__device__ __constant__ const signed char c_strip[NCHUNK] =
    {0,1,2,3, 4,4, 5,5, 6,6, 7,7, 8,8,8, 9,9,9, 10,10,10, 11,11,11,
     12,12,12,12, 13,13,13,13, 14,14,14,14, 15,15,15,15};
__device__ __constant__ const signed char c_chunk[NCHUNK] =
    {0,0,0,0, 0,1, 0,1, 0,1, 0,1, 0,1,2, 0,1,2, 0,1,2, 0,1,2,
     0,1,2,3, 0,1,2,3, 0,1,2,3, 0,1,2,3};
__device__ __constant__ const signed char c_cbase[16] = {0,1,2,3,4,6,8,10,12,15,18,21,24,28,32,36};
__device__ __constant__ const signed char c_nch[16]   = {1,1,1,1,2,2,2,2,3,3,3,3,4,4,4,4};

// ---------------- Prep: ln1(bf16) + conv(qkvW) + conv(projW) ----------------
__global__ __launch_bounds__(256)
void prep_kernel(const float* __restrict__ hidden, const float* __restrict__ ln1w,
                 const float* __restrict__ ln1bb, const float* __restrict__ qkvW,
                 const float* __restrict__ projW, __bf16* __restrict__ ln1o,
                 __bf16* __restrict__ projWb, __bf16* __restrict__ qkvWb) {
    const int b = blockIdx.x, tid = threadIdx.x;
    if (b < S_LEN) {
        __shared__ float red[256];
        const float* x = hidden + (size_t)b * HDIM;
        float xr[4];
        #pragma unroll
        for (int j = 0; j < 4; ++j) xr[j] = x[tid + 256*j];
        float s = xr[0] + xr[1] + xr[2] + xr[3];
        red[tid] = s; __syncthreads();
        for (int st = 128; st > 0; st >>= 1) { if (tid < st) red[tid] += red[tid+st]; __syncthreads(); }
        float mu = red[0] / HDIM; __syncthreads();
        float v = 0.f;
        #pragma unroll
        for (int j = 0; j < 4; ++j) { float d = xr[j]-mu; v += d*d; }
        red[tid] = v; __syncthreads();
        for (int st = 128; st > 0; st >>= 1) { if (tid < st) red[tid] += red[tid+st]; __syncthreads(); }
        float rstd = rsqrtf(red[0]/HDIM + 1e-5f);
        #pragma unroll
        for (int j = 0; j < 4; ++j) {
            int i = tid + 256*j;
            ln1o[(size_t)b*HDIM + i] = (__bf16)((xr[j]-mu)*rstd*ln1w[i] + ln1bb[i]);
        }
        return;
    }
    const float* src; __bf16* dst; int i;
    if (b < S_LEN + 768) { src = qkvW; dst = qkvWb; i = (b - S_LEN)*256 + tid; }
    else                 { src = projW; dst = projWb; i = (b - S_LEN - 768)*256 + tid; }
    const float4* s = (const float4*)src + (size_t)i*2;
    float4 a = s[0], b4 = s[1];
    __bf16 tmp[8] = {(__bf16)a.x,(__bf16)a.y,(__bf16)a.z,(__bf16)a.w,
                     (__bf16)b4.x,(__bf16)b4.y,(__bf16)b4.z,(__bf16)b4.w};
    *(u32x4*)(dst + (size_t)i*8) = *(u32x4*)tmp;
}

// ---------------- bf16 MFMA GEMM, BM=64 x BN=128, Bt bf16 [N][K] (qkv/proj) ----------------
template<int EPI>
__global__ __launch_bounds__(256)
void gemm64_bf16_kernel(const __bf16* __restrict__ A, const __bf16* __restrict__ Bt,
                        const float* __restrict__ R, void* __restrict__ Cout,
                        int N, int K, long sA, long sB, long sC) {
    __shared__ __bf16 As[64*64];
    __shared__ __bf16 Bs[128*64];
    const int e = blockIdx.z;
    A  += (size_t)e * sA;
    Bt += (size_t)e * sB;
    const int m0 = blockIdx.y*64, n0 = blockIdx.x*128;
    const int tid = threadIdx.x;
    const int lane = tid & 63, w = tid >> 6;
    const int lr = lane & 15, lg = lane >> 4;
    const int srow8 = lane >> 3, sg = lane & 7;
    f32x4 acc[4][2] = {};
    for (int k0 = 0; k0 < K; k0 += 64) {
        __syncthreads();
        #pragma unroll
        for (int i = 0; i < 2; ++i) {
            int row = 16*w + 8*i + srow8;
            int src_g = sg ^ (row & 7);
            gload16(A + (size_t)(m0+row)*K + k0 + src_g*8,
                    (__bf16*)((char*)As + (16*w + 8*i)*128));
        }
        #pragma unroll
        for (int i = 0; i < 4; ++i) {
            int row = 32*w + 8*i + srow8;
            int src_g = sg ^ (row & 7);
            gload16(Bt + (size_t)(n0+row)*K + k0 + src_g*8,
                    (__bf16*)((char*)Bs + (32*w + 8*i)*128));
        }
        __syncthreads();
        #pragma unroll
        for (int ks = 0; ks < 2; ++ks) {
            bf16x8 af[4], bfr[2];
            #pragma unroll
            for (int mi = 0; mi < 4; ++mi) {
                int row = mi*16 + lr;
                af[mi] = *(const bf16x8*)((const char*)As + ((row*128 + (lg+4*ks)*16) ^ ((row&7)<<4)));
            }
            #pragma unroll
            for (int ni = 0; ni < 2; ++ni) {
                int row = w*32 + ni*16 + lr;
                bfr[ni] = *(const bf16x8*)((const char*)Bs + ((row*128 + (lg+4*ks)*16) ^ ((row&7)<<4)));
            }
            #pragma unroll
            for (int mi = 0; mi < 4; ++mi)
                #pragma unroll
                for (int ni = 0; ni < 2; ++ni)
                    acc[mi][ni] = __builtin_amdgcn_mfma_f32_16x16x32_bf16(af[mi], bfr[ni], acc[mi][ni], 0,0,0);
        }
    }
    #pragma unroll
    for (int mi = 0; mi < 4; ++mi) {
        #pragma unroll
        for (int ni = 0; ni < 2; ++ni) {
            #pragma unroll
            for (int r = 0; r < 4; ++r) {
                int row = m0 + mi*16 + lg*4 + r;
                int col = n0 + w*32 + ni*16 + lr;
                float v = acc[mi][ni][r];
                if (EPI == 1) v += R[(size_t)row*N + col];
                if (EPI == 2) {
                    float t = 0.7978845608028654f * (v + 0.044715f*v*v*v);
                    v = 0.5f * v * (1.f + tanhf(t));
                }
                if (EPI == 2 || EPI == 3)
                    ((__bf16*)Cout)[(size_t)e*sC + (size_t)row*N + col] = (__bf16)v;
                else
                    ((float*)Cout)[(size_t)e*sC + (size_t)row*N + col] = v;
            }
        }
    }
}

// ---------------- bf16 MFMA GEMM, BM=64, W bf16 [K][N] transposed-in-staging (fc1/fc2) ----------------
template<int EPI>
__global__ __launch_bounds__(256)
void gemm64t_bf16_kernel(const __bf16* __restrict__ A, const __bf16* __restrict__ Wb,
                         const float* __restrict__ R, void* __restrict__ Cout,
                         int N, int K, long sA, long sB, long sC) {
    __shared__ __bf16 As[64*64];
    __shared__ __bf16 Bs[128*64];
    const int e = blockIdx.z;
    A  += (size_t)e * sA;
    Wb += (size_t)e * sB;
    const int m0 = blockIdx.y*64, n0 = blockIdx.x*128;
    const int tid = threadIdx.x;
    const int lane = tid & 63, w = tid >> 6;
    const int lr = lane & 15, lg = lane >> 4;
    const int srow8 = lane >> 3, sg = lane & 7;
    const int nc = tid & 7, kp = tid >> 3;
    u16x8 wr0a, wr0b, wr1a, wr1b;

#define ISSUE_B(K0) do { \
        const __bf16* p = Wb + (size_t)((K0) + 2*kp)*N + n0 + nc*16; \
        wr0a = *(const u16x8*)(p); \
        wr0b = *(const u16x8*)(p + 8); \
        wr1a = *(const u16x8*)(p + N); \
        wr1b = *(const u16x8*)(p + N + 8); \
    } while(0)

#define COMMIT_B() do { \
        _Pragma("unroll") \
        for (int j = 0; j < 8; ++j) { \
            int n = nc*16 + j; \
            u32 u = ((u32)wr1a[j] << 16) | wr0a[j]; \
            *(u32*)((char*)Bs + ((n*128 + kp*4) ^ ((n&7)<<4))) = u; \
        } \
        _Pragma("unroll") \
        for (int j = 0; j < 8; ++j) { \
            int n = nc*16 + 8 + j; \
            u32 u = ((u32)wr1b[j] << 16) | wr0b[j]; \
            *(u32*)((char*)Bs + ((n*128 + kp*4) ^ ((n&7)<<4))) = u; \
        } \
    } while(0)

    f32x4 acc[4][2] = {};
    ISSUE_B(0);
    for (int k0 = 0; k0 < K; k0 += 64) {
        __syncthreads();
        COMMIT_B();
        #pragma unroll
        for (int i = 0; i < 2; ++i) {
            int row = 16*w + 8*i + srow8;
            int src_g = sg ^ (row & 7);
            gload16(A + (size_t)(m0+row)*K + k0 + src_g*8,
                    (__bf16*)((char*)As + (16*w + 8*i)*128));
        }
        if (k0 + 64 < K) ISSUE_B(k0 + 64);
        __syncthreads();
        #pragma unroll
        for (int ks = 0; ks < 2; ++ks) {
            bf16x8 af[4], bfr[2];
            #pragma unroll
            for (int mi = 0; mi < 4; ++mi) {
                int row = mi*16 + lr;
                af[mi] = *(const bf16x8*)((const char*)As + ((row*128 + (lg+4*ks)*16) ^ ((row&7)<<4)));
            }
            #pragma unroll
            for (int ni = 0; ni < 2; ++ni) {
                int row = w*32 + ni*16 + lr;
                bfr[ni] = *(const bf16x8*)((const char*)Bs + ((row*128 + (lg+4*ks)*16) ^ ((row&7)<<4)));
            }
            #pragma unroll
            for (int mi = 0; mi < 4; ++mi)
                #pragma unroll
                for (int ni = 0; ni < 2; ++ni)
                    acc[mi][ni] = __builtin_amdgcn_mfma_f32_16x16x32_bf16(af[mi], bfr[ni], acc[mi][ni], 0,0,0);
        }
    }
#undef ISSUE_B
#undef COMMIT_B
    #pragma unroll
    for (int mi = 0; mi < 4; ++mi) {
        #pragma unroll
        for (int ni = 0; ni < 2; ++ni) {
            #pragma unroll
            for (int r = 0; r < 4; ++r) {
                int row = m0 + mi*16 + lg*4 + r;
                int col = n0 + w*32 + ni*16 + lr;
                float v = acc[mi][ni][r];
                if (EPI == 1) v += R[(size_t)row*N + col];
                if (EPI == 2) {
                    float t = 0.7978845608028654f * (v + 0.044715f*v*v*v);
                    v = 0.5f * v * (1.f + tanhf(t));
                }
                if (EPI == 2 || EPI == 3)
                    ((__bf16*)Cout)[(size_t)e*sC + (size_t)row*N + col] = (__bf16)v;
                else
                    ((float*)Cout)[(size_t)e*sC + (size_t)row*N + col] = v;
            }
        }
    }
}

// ---------------- FUSED: attention partials ∥ w1/w2 f32->bf16 convert (interleaved, MOD=13) ----------------
__global__ __launch_bounds__(512)
void attn_conv_kernel(const __bf16* __restrict__ qkv, float* __restrict__ partO,
                      float* __restrict__ partML,
                      const float* __restrict__ w1, const float* __restrict__ w2,
                      __bf16* __restrict__ w1b, __bf16* __restrict__ w2b) {
    __shared__ __attribute__((aligned(16))) char smem[49152];
    const int bid = blockIdx.x;
    const bool is_attn = ((bid % 13) == 6) && (bid / 13 < ATTN_BLOCKS);

    if (!is_attn) {
        // convert path: 4096 f32 -> bf16, coalesced both sides
        const int cv = bid - min(ATTN_BLOCKS, (bid + 6) / 13);   // 0..8191 (verified)
        const float* src; __bf16* dst;
        size_t off;
        if (cv < 4096) { src = w1; dst = w1b; off = (size_t)cv * 4096; }
        else           { src = w2; dst = w2b; off = (size_t)(cv - 4096) * 4096; }
        const int i = threadIdx.x;
        const float4* s = (const float4*)(src + off) + (size_t)i*2;
        float4 a = s[0], b4 = s[1];
        __bf16 tmp[8] = {(__bf16)a.x,(__bf16)a.y,(__bf16)a.z,(__bf16)a.w,
                         (__bf16)b4.x,(__bf16)b4.y,(__bf16)b4.z,(__bf16)b4.w};
        *(u32x4*)(dst + off + (size_t)i*8) = *(u32x4*)tmp;
        return;
    }

    // ---- attention path
    __bf16* Kls = (__bf16*)smem;
    __bf16* Vls = (__bf16*)(smem + 16384);
    const int a = bid / 13;
    const int cx = a % NCHUNK;
    const int h  = a / NCHUNK;
    const int hg = h >> 2, qi = h & 3;
    const int qb = c_strip[cx];
    const int t0 = 4 * c_chunk[cx];
    const int t1 = min(qb + 1, t0 + 4);
    const int q0 = qb * 128;
    const int tid  = threadIdx.x;
    const int w    = tid >> 6;
    const int lane = tid & 63;
    const int lr   = lane & 15;
    const int lg   = lane >> 4;

    const int krow = tid >> 2, kc = (tid & 3) * 2;
    const int va = tid & 63,  dg  = tid >> 6;
    u32x4 kreg[2]; u16x8 vreg[2];

    const __bf16* kbase = qkv + hg*384 + 256;
    const __bf16* vbase = qkv + hg*384 + 320;

#define ISSUE(T) do { \
        const __bf16* kp = kbase + (size_t)((T)*128 + krow)*QKV_O + kc*8; \
        kreg[0] = *(const u32x4*)(kp); \
        kreg[1] = *(const u32x4*)(kp + 8); \
        const __bf16* vp = vbase + (size_t)((T)*128 + 2*va)*QKV_O + dg*8; \
        vreg[0] = *(const u16x8*)(vp); \
        vreg[1] = *(const u16x8*)(vp + QKV_O); \
    } while(0)

#define COMMIT() do { \
        char* Kb = (char*)Kls; \
        *(u32x4*)(Kb + ((krow*128 + (kc+0)*16) ^ ((krow&7)<<4))) = kreg[0]; \
        *(u32x4*)(Kb + ((krow*128 + (kc+1)*16) ^ ((krow&7)<<4))) = kreg[1]; \
        char* Vb = (char*)Vls; \
        _Pragma("unroll") \
        for (int j = 0; j < 8; ++j) { \
            int d = dg*8 + j; \
            u32 u = ((u32)vreg[1][j] << 16) | vreg[0][j]; \
            *(u32*)(Vb + ((d*256 + va*4) ^ ((d&7)<<4))) = u; \
        } \
    } while(0)

    const int qrow = q0 + w*16 + lr;
    const __bf16* qp = qkv + (size_t)qrow*QKV_O + hg*384 + qi*64;
    bf16x8 qfrag[2];
    #pragma unroll
    for (int ks = 0; ks < 2; ++ks) {
        bf16x8 qr = *(const bf16x8*)(qp + ks*32 + lg*8);
        #pragma unroll
        for (int j = 0; j < 8; ++j) qfrag[ks][j] = (__bf16)((float)qr[j] * 0.125f);
    }
    bf16x8 ones;
    #pragma unroll
    for (int j = 0; j < 8; ++j) ones[j] = (__bf16)1.0f;

    f32x4 oacc[4] = {};
    f32x4 lcol = {};
    float mrow[4] = {-INFINITY,-INFINITY,-INFINITY,-INFINITY};

    ISSUE(t0);
    for (int t = t0; t < t1; ++t) {
        __syncthreads();
        COMMIT();
        if (t+1 < t1) ISSUE(t+1);
        __syncthreads();

        f32x4 sacc[8] = {};
        const char* Kb = (const char*)Kls;
        #pragma unroll
        for (int f = 0; f < 8; ++f) {
            int row = lr + 16*f;
            int swz = (row & 7) << 4;
            #pragma unroll
            for (int ks = 0; ks < 2; ++ks) {
                bf16x8 kf = *(const bf16x8*)(Kb + ((row*128 + (lg*8+32*ks)*2) ^ swz));
                sacc[f] = __builtin_amdgcn_mfma_f32_16x16x32_bf16(qfrag[ks], kf, sacc[f], 0,0,0);
            }
        }
        if (t == qb) {
            #pragma unroll
            for (int f = 0; f < 8; ++f)
                #pragma unroll
                for (int r = 0; r < 4; ++r)
                    if (lr + 16*f > 16*w + 4*lg + r) sacc[f][r] = -INFINITY;
        }
        float tm[4];
        #pragma unroll
        for (int r = 0; r < 4; ++r) {
            float a2 = fmaxf(fmaxf(sacc[0][r], sacc[1][r]), fmaxf(sacc[2][r], sacc[3][r]));
            float b2 = fmaxf(fmaxf(sacc[4][r], sacc[5][r]), fmaxf(sacc[6][r], sacc[7][r]));
            tm[r] = fmaxf(a2, b2);
        }
        #pragma unroll
        for (int msk = 1; msk < 16; msk <<= 1)
            #pragma unroll
            for (int r = 0; r < 4; ++r) tm[r] = fmaxf(tm[r], __shfl_xor(tm[r], msk, 64));
        float corr[4];
        #pragma unroll
        for (int r = 0; r < 4; ++r) {
            float mn = fmaxf(mrow[r], tm[r]);
            corr[r] = exp2f((mrow[r]-mn)*LOG2E);
            mrow[r] = mn;
        }
        #pragma unroll
        for (int f = 0; f < 8; ++f)
            #pragma unroll
            for (int r = 0; r < 4; ++r)
                sacc[f][r] = exp2f((sacc[f][r]-mrow[r])*LOG2E);
        #pragma unroll
        for (int ct = 0; ct < 4; ++ct)
            #pragma unroll
            for (int r = 0; r < 4; ++r) oacc[ct][r] *= corr[r];
        #pragma unroll
        for (int r = 0; r < 4; ++r) lcol[r] *= corr[r];

        char* Pw = smem + 32768 + w*2048;
        const char* Vb = (const char*)Vls;
        #pragma unroll
        for (int half = 0; half < 2; ++half) {
            #pragma unroll
            for (int f = 0; f < 4; ++f)
                #pragma unroll
                for (int r = 0; r < 4; ++r) {
                    int row = 4*lg + r, col = lr + 16*f;
                    *(__bf16*)(Pw + ((row*128 + col*2) ^ ((row&7)<<4))) = (__bf16)sacc[4*half+f][r];
                }
            bf16x8 pa[2];
            #pragma unroll
            for (int ks = 0; ks < 2; ++ks)
                pa[ks] = *(const bf16x8*)(Pw + ((lr*128 + (lg*8+32*ks)*2) ^ ((lr&7)<<4)));
            #pragma unroll
            for (int ks = 0; ks < 2; ++ks)
                lcol = __builtin_amdgcn_mfma_f32_16x16x32_bf16(pa[ks], ones, lcol, 0,0,0);
            #pragma unroll
            for (int ct = 0; ct < 4; ++ct) {
                int row = lr + 16*ct;
                int swz = (row & 7) << 4;
                #pragma unroll
                for (int ks = 0; ks < 2; ++ks) {
                    int gks = 2*half + ks;
                    bf16x8 vf = *(const bf16x8*)(Vb + ((row*256 + (lg*8+32*gks)*2) ^ swz));
                    oacc[ct] = __builtin_amdgcn_mfma_f32_16x16x32_bf16(pa[ks], vf, oacc[ct], 0,0,0);
                }
            }
        }
    }
    const int p = h*NCHUNK + cx;
    float* po = partO + (size_t)p * (128*64);
    #pragma unroll
    for (int ct = 0; ct < 4; ++ct)
        #pragma unroll
        for (int r = 0; r < 4; ++r)
            po[(16*w + 4*lg + r)*64 + 16*ct + lr] = oacc[ct][r];
    if (lr == 0) {
        float* pm = partML + (size_t)p * 256;
        #pragma unroll
        for (int r = 0; r < 4; ++r) {
            pm[(16*w + 4*lg + r)*2    ] = mrow[r];
            pm[(16*w + 4*lg + r)*2 + 1] = lcol[r];
        }
    }
#undef ISSUE
#undef COMMIT
}

// ---------------- Flash combine ----------------
__global__ __launch_bounds__(256)
void attn_combine_kernel(const float* __restrict__ partO, const float* __restrict__ partML,
                         __bf16* __restrict__ ao) {
    const int rb = blockIdx.x, h = blockIdx.y;
    const int row0 = rb*8;
    const int qb = row0 >> 7;
    const int nc = c_nch[qb], cb = c_cbase[qb];
    const int tid = threadIdx.x;
    const int rl = tid >> 5, d2 = (tid & 31) * 2;
    const int grow = row0 + rl;
    const int srow = grow & 127;
    const int pbase = h*NCHUNK + cb;
    float mv[4], lv[4];
    float M = -INFINITY;
    for (int c = 0; c < nc; ++c) {
        const float* pm = partML + (size_t)(pbase+c)*256 + srow*2;
        mv[c] = pm[0]; lv[c] = pm[1];
        M = fmaxf(M, mv[c]);
    }
    float L = 0.f, a0 = 0.f, a1 = 0.f;
    for (int c = 0; c < nc; ++c) {
        float wc = exp2f((mv[c]-M)*LOG2E);
        L += wc * lv[c];
        const float* po = partO + (size_t)(pbase+c)*(128*64) + srow*64 + d2;
        a0 += wc * po[0];
        a1 += wc * po[1];
    }
    float inv = 1.f / L;
    __bf16 o2[2] = {(__bf16)(a0*inv), (__bf16)(a1*inv)};
    *(u32*)(ao + (size_t)grow*HDIM + h*64 + d2) = *(u32*)o2;
}

// ---------------- Fused LN2 + Router ----------------
__global__ __launch_bounds__(256)
void ln2_router_kernel(const float* __restrict__ h1, const float* __restrict__ w,
                       const float* __restrict__ b, const float* __restrict__ rw,
                       __bf16* __restrict__ x2b, int* __restrict__ expi,
                       float* __restrict__ expp) {
    const int t = blockIdx.x, tid = threadIdx.x;
    __shared__ float red[256];
    __shared__ float red8[256][8];
    const float* x = h1 + (size_t)t*HDIM;
    float xr[4];
    #pragma unroll
    for (int j = 0; j < 4; ++j) xr[j] = x[tid + 256*j];
    float s = xr[0] + xr[1] + xr[2] + xr[3];
    red[tid] = s; __syncthreads();
    for (int st = 128; st > 0; st >>= 1) { if (tid < st) red[tid] += red[tid+st]; __syncthreads(); }
    float mu = red[0] / HDIM; __syncthreads();
    float v = 0.f;
    #pragma unroll
    for (int j = 0; j < 4; ++j) { float d = xr[j]-mu; v += d*d; }
    red[tid] = v; __syncthreads();
    for (int st = 128; st > 0; st >>= 1) { if (tid < st) red[tid] += red[tid+st]; __syncthreads(); }
    float rstd = rsqrtf(red[0]/HDIM + 1e-5f);
    float part[8] = {};
    #pragma unroll
    for (int j = 0; j < 4; ++j) {
        int i = tid + 256*j;
        float o = (xr[j]-mu)*rstd*w[i] + b[i];
        x2b[(size_t)t*HDIM + i] = (__bf16)o;
        const float* wp = rw + (size_t)i*NEXP;
        #pragma unroll
        for (int e2 = 0; e2 < 8; ++e2) part[e2] += o * wp[e2];
    }
    #pragma unroll
    for (int e2 = 0; e2 < 8; ++e2) red8[tid][e2] = part[e2];
    __syncthreads();
    for (int st = 128; st > 0; st >>= 1) {
        if (tid < st)
            #pragma unroll
            for (int e2 = 0; e2 < 8; ++e2) red8[tid][e2] += red8[tid+st][e2];
        __syncthreads();
    }
    if (tid == 0) {
        float lg[8];
        #pragma unroll
        for (int e2 = 0; e2 < 8; ++e2) lg[e2] = red8[0][e2];
        int i0 = 0;
        for (int e2 = 1; e2 < 8; ++e2) if (lg[e2] > lg[i0]) i0 = e2;
        int i1 = -1;
        for (int e2 = 0; e2 < 8; ++e2) { if (e2 == i0) continue; if (i1 < 0 || lg[e2] > lg[i1]) i1 = e2; }
        float p1 = __expf(lg[i1] - lg[i0]);
        float inv = 1.f / (1.f + p1);
        expi[t*2]   = i0; expi[t*2+1] = i1;
        expp[t*2]   = inv; expp[t*2+1] = p1 * inv;
    }
}

// ---------------- Stable rank -> destination ----------------
__global__ __launch_bounds__(256)
void dst_fast_kernel(const int* __restrict__ expi, int* __restrict__ dst) {
    __shared__ int hist[256][9];
    const int tid = threadIdx.x;
    int ev[16];
    #pragma unroll
    for (int i = 0; i < 16; i += 4)
        *(int4*)(ev+i) = *(const int4*)(expi + tid*16 + i);
    int cnt[8] = {};
    #pragma unroll
    for (int i = 0; i < 16; ++i)
        #pragma unroll
        for (int e = 0; e < 8; ++e) cnt[e] += (ev[i] == e);
    #pragma unroll
    for (int e = 0; e < 8; ++e) hist[tid][e] = cnt[e];
    __syncthreads();
    const int w = tid >> 6, lane = tid & 63;
    #pragma unroll
    for (int rep = 0; rep < 2; ++rep) {
        int e = w + rep*4;
        int h0 = hist[4*lane+0][e], h1 = hist[4*lane+1][e],
            h2 = hist[4*lane+2][e], h3 = hist[4*lane+3][e];
        int s = h0+h1+h2+h3, inc = s;
        #pragma unroll
        for (int off = 1; off < 64; off <<= 1) {
            int v = __shfl_up(inc, off, 64);
            if (lane >= off) inc += v;
        }
        int excl = inc - s;
        hist[4*lane+0][e] = excl;
        hist[4*lane+1][e] = excl + h0;
        hist[4*lane+2][e] = excl + h0 + h1;
        hist[4*lane+3][e] = excl + h0 + h1 + h2;
    }
    __syncthreads();
    int run[8];
    #pragma unroll
    for (int e = 0; e < 8; ++e) run[e] = hist[tid][e];
    int out[16];
    #pragma unroll
    for (int i = 0; i < 16; ++i) {
        int e = ev[i], within = 0;
        #pragma unroll
        for (int e2 = 0; e2 < 8; ++e2)
            if (e == e2) { within = run[e2]; run[e2]++; }
        out[i] = (within < CAP) ? (e*CAP + within) : -1;
    }
    #pragma unroll
    for (int i = 0; i < 16; i += 4)
        *(int4*)(dst + tid*16 + i) = *(const int4*)(out+i);
}

// ---------------- Scatter ----------------
__global__ void scatter_kernel(const __bf16* __restrict__ x2b, const int* __restrict__ dst,
                               __bf16* __restrict__ xt) {
    int s = blockIdx.x;
    int d = dst[s];
    if (d < 0) return;
    int t = s >> 1;
    int i = threadIdx.x;
    u32x2 v = *(const u32x2*)(x2b + (size_t)t*HDIM + i*4);
    *(u32x2*)(xt + (size_t)d*HDIM + i*4) = v;
}

// ---------------- Combine (MoE) ----------------
__global__ void combine_kernel(const float* __restrict__ h1, const float* __restrict__ fc2,
                               const int* __restrict__ dst, const float* __restrict__ expp,
                               float* __restrict__ out) {
    int t = blockIdx.x;
    int d0 = dst[t*2], d1 = dst[t*2+1];
    float p0 = expp[t*2], p1 = expp[t*2+1];
    int i = threadIdx.x * 4;
    float4 v = *(const float4*)(h1 + (size_t)t*HDIM + i);
    if (d0 >= 0) {
        float4 f = *(const float4*)(fc2 + (size_t)d0*HDIM + i);
        v.x += p0*f.x; v.y += p0*f.y; v.z += p0*f.z; v.w += p0*f.w;
    }
    if (d1 >= 0) {
        float4 f = *(const float4*)(fc2 + (size_t)d1*HDIM + i);
        v.x += p1*f.x; v.y += p1*f.y; v.z += p1*f.z; v.w += p1*f.w;
    }
    *(float4*)(out + (size_t)t*HDIM + i) = v;
}

extern "C" void kernel_launch(void* const* d_in, const int* in_sizes, int n_in,
                              void* d_out, int out_size, void* d_ws, size_t ws_size,
                              hipStream_t stream) {
    const float* hidden = (const float*)d_in[0];
    const float* ln1w   = (const float*)d_in[1];
    const float* ln1b_  = (const float*)d_in[2];
    const float* ln2w   = (const float*)d_in[3];
    const float* ln2b_  = (const float*)d_in[4];
    const float* qkvW   = (const float*)d_in[5];
    const float* projW  = (const float*)d_in[6];
    const float* routW  = (const float*)d_in[7];
    const float* w1     = (const float*)d_in[8];
    const float* w2     = (const float*)d_in[9];
    float* out = (float*)d_out;

    // Arena (lifetime-audited; as round 16 with w1b/w2b [K][N] bf16)
    char* base = (char*)d_ws;
    __bf16* w1b    = (__bf16*)(base);                 // [E][H][F] bf16, written step 3
    __bf16* w2b    = (__bf16*)(base + 33554432);      // [E][F][H] bf16
    __bf16* ln1b   = (__bf16*)(base);                 // alias: dead before step 3
    __bf16* qkvWb  = (__bf16*)(base + 4194304);       // alias: dead before step 3
    char* B0 = base + 67108864;
    float*  h1   = (float*)(B0);
    __bf16* xtb  = (__bf16*)(B0 + 8388608);
    __bf16* fc1b = (__bf16*)(B0 + 18874368);
    float*  fc2  = (float*)(B0 + 39845888);
    __bf16* x2b    = (__bf16*)fc2;
    __bf16* qkvb   = (__bf16*)((char*)fc2 + 4194304);
    __bf16* aob    = (__bf16*)((char*)fc2 + 10485760);
    __bf16* projWb = (__bf16*)((char*)fc2 + 14680064);
    int*    expi = (int*)(B0 + 60817408);
    int*    dsts = (int*)(B0 + 60833792);
    float*  expp = (float*)(B0 + 60850176);
    float*  partML = (float*)xtb;
    float*  partO  = (float*)fc1b;

    // 1. prep
    prep_kernel<<<S_LEN + 768 + 512, 256, 0, stream>>>(
        hidden, ln1w, ln1b_, qkvW, projW, ln1b, projWb, qkvWb);
    // 2. QKV (BM64)
    gemm64_bf16_kernel<3><<<dim3(QKV_O/128, S_LEN/64, 1), 256, 0, stream>>>(
        ln1b, qkvWb, nullptr, qkvb, QKV_O, HDIM, 0, 0, 0);
    // 3. FUSED attention ∥ w1/w2 convert (interleaved, fixed MOD=13 mapping)
    attn_conv_kernel<<<ATTN_BLOCKS + CONV_BLOCKS, 512, 0, stream>>>(
        qkvb, partO, partML, w1, w2, w1b, w2b);
    // 4. attention combine -> aob
    attn_combine_kernel<<<dim3(S_LEN/8, NHEAD), 256, 0, stream>>>(partO, partML, aob);
    // 5. h1 = hidden + ao @ projW^T (BM64)
    gemm64_bf16_kernel<1><<<dim3(HDIM/128, S_LEN/64, 1), 256, 0, stream>>>(
        aob, projWb, hidden, h1, HDIM, HDIM, 0, 0, 0);
    // 6. LN2 + router
    ln2_router_kernel<<<S_LEN, 256, 0, stream>>>(h1, ln2w, ln2b_, routW, x2b, expi, expp);
    // 7. slots
    dst_fast_kernel<<<1, 256, 0, stream>>>(expi, dsts);
    // 8. scatter
    scatter_kernel<<<S_LEN*TOPK, 256, 0, stream>>>(x2b, dsts, xtb);
    // 9. FC1 = gelu(xt @ w1) (BM64, in-staging transpose from bf16 [H][F])
    gemm64t_bf16_kernel<2><<<dim3(FDIM/128, CAP/64, NEXP), 256, 0, stream>>>(
        xtb, w1b, nullptr, fc1b, FDIM, HDIM,
        (long)CAP*HDIM, (long)HDIM*FDIM, (long)CAP*FDIM);
    // 10. FC2 = fc1 @ w2 (BM64, in-staging transpose from bf16 [F][H])
    gemm64t_bf16_kernel<0><<<dim3(HDIM/128, CAP/64, NEXP), 256, 0, stream>>>(
        fc1b, w2b, nullptr, fc2, HDIM, FDIM,
        (long)CAP*FDIM, (long)FDIM*HDIM, (long)CAP*HDIM);
    // 11. combine
    combine_kernel<<<S_LEN, 256, 0, stream>>>(h1, fc2, dsts, expp, out);
}

// Round 20
// 228.927 us; speedup vs baseline: 1.2894x; 1.2894x over previous
//
#include <hip/hip_runtime.h>
#include <hip/hip_bf16.h>
#include <stdint.h>

#define S_LEN 2048
#define HDIM  1024
#define NHEAD 16
#define NKVH  4
#define HEADD 64
#define QKV_O 1536   // NKV*(q_per_kv+2)*HD = 4*6*64
#define NEXP  8
#define TOPK  2
#define CAP   640    // ceil(2048*2/8*1.25)
#define TCAP  (NEXP*CAP)
#define FDIM  2048
#define LOG2E 1.44269504088896f
#define NCHUNK 40    // per head: sum over 16 strips of ceil((qb+1)/4)
#define ATTN_BLOCKS (NCHUNK*NHEAD)   // 640
#define TRANSP_BLOCKS 4096           // 8192 tiles / 2 per block

typedef __bf16 bf16x8 __attribute__((ext_vector_type(8)));
typedef float  f32x4  __attribute__((ext_vector_type(4)));
typedef unsigned int u32;
typedef u32 u32x4 __attribute__((ext_vector_type(4)));
typedef u32 u32x2 __attribute__((ext_vector_type(2)));
typedef unsigned short u16;
typedef u16 u16x8 __attribute__((ext_vector_type(8)));

// async global->LDS, 16B per lane; LDS dest is wave-uniform base + lane*16
__device__ __forceinline__ void gload16(const __bf16* g, __bf16* l) {
    __builtin_amdgcn_global_load_lds(
        (const __attribute__((address_space(1))) u32*)g,
        (__attribute__((address_space(3))) u32*)l, 16, 0, 0);
}

// chunk tables
__device__ __constant__ const signed char c_strip[NCHUNK] =
    {0,1,2,3, 4,4, 5,5, 6,6, 7,7, 8,8,8, 9,9,9, 10,10,10, 11,11,11,
     12,12,12,12, 13,13,13,13, 14,14,14,14, 15,15,15,15};
__device__ __constant__ const signed char c_chunk[NCHUNK] =
    {0,0,0,0, 0,1, 0,1, 0,1, 0,1, 0,1,2, 0,1,2, 0,1,2, 0,1,2,
     0,1,2,3, 0,1,2,3, 0,1,2,3, 0,1,2,3};
__device__ __constant__ const signed char c_cbase[16] = {0,1,2,3,4,6,8,10,12,15,18,21,24,28,32,36};
__device__ __constant__ const signed char c_nch[16]   = {1,1,1,1,2,2,2,2,3,3,3,3,4,4,4,4};

// ---------------- Prep: ln1(bf16) + conv(qkvW) + conv(projW) ----------------
__global__ __launch_bounds__(256)
void prep_kernel(const float* __restrict__ hidden, const float* __restrict__ ln1w,
                 const float* __restrict__ ln1bb, const float* __restrict__ qkvW,
                 const float* __restrict__ projW, __bf16* __restrict__ ln1o,
                 __bf16* __restrict__ projWb, __bf16* __restrict__ qkvWb) {
    const int b = blockIdx.x, tid = threadIdx.x;
    if (b < S_LEN) {
        __shared__ float red[256];
        const float* x = hidden + (size_t)b * HDIM;
        float xr[4];
        #pragma unroll
        for (int j = 0; j < 4; ++j) xr[j] = x[tid + 256*j];
        float s = xr[0] + xr[1] + xr[2] + xr[3];
        red[tid] = s; __syncthreads();
        for (int st = 128; st > 0; st >>= 1) { if (tid < st) red[tid] += red[tid+st]; __syncthreads(); }
        float mu = red[0] / HDIM; __syncthreads();
        float v = 0.f;
        #pragma unroll
        for (int j = 0; j < 4; ++j) { float d = xr[j]-mu; v += d*d; }
        red[tid] = v; __syncthreads();
        for (int st = 128; st > 0; st >>= 1) { if (tid < st) red[tid] += red[tid+st]; __syncthreads(); }
        float rstd = rsqrtf(red[0]/HDIM + 1e-5f);
        #pragma unroll
        for (int j = 0; j < 4; ++j) {
            int i = tid + 256*j;
            ln1o[(size_t)b*HDIM + i] = (__bf16)((xr[j]-mu)*rstd*ln1w[i] + ln1bb[i]);
        }
        return;
    }
    const float* src; __bf16* dst; int i;
    if (b < S_LEN + 768) { src = qkvW; dst = qkvWb; i = (b - S_LEN)*256 + tid; }
    else                 { src = projW; dst = projWb; i = (b - S_LEN - 768)*256 + tid; }
    const float4* s = (const float4*)src + (size_t)i*2;
    float4 a = s[0], b4 = s[1];
    __bf16 tmp[8] = {(__bf16)a.x,(__bf16)a.y,(__bf16)a.z,(__bf16)a.w,
                     (__bf16)b4.x,(__bf16)b4.y,(__bf16)b4.z,(__bf16)b4.w};
    *(u32x4*)(dst + (size_t)i*8) = *(u32x4*)tmp;
}

// ---------------- bf16 MFMA GEMM, BM=128 (fc1): C = A * Bt^T ----------------
template<int EPI>
__global__ __launch_bounds__(256)
void gemm_bf16_kernel(const __bf16* __restrict__ A, const __bf16* __restrict__ Bt,
                      const float* __restrict__ R, void* __restrict__ Cout,
                      int N, int K, long sA, long sB, long sC) {
    __shared__ __bf16 As[128*64];
    __shared__ __bf16 Bs[128*64];
    const int e = blockIdx.z;
    A  += (size_t)e * sA;
    Bt += (size_t)e * sB;
    const int m0 = blockIdx.y*128, n0 = blockIdx.x*128;
    const int tid = threadIdx.x;
    const int lane = tid & 63, w = tid >> 6;
    const int lr = lane & 15, lg = lane >> 4;
    const int wr = w >> 1, wc = w & 1;
    const int srow8 = lane >> 3, sg = lane & 7;
    f32x4 acc[4][4] = {};
    for (int k0 = 0; k0 < K; k0 += 64) {
        __syncthreads();
        #pragma unroll
        for (int i = 0; i < 4; ++i) {
            int row = 32*w + 8*i + srow8;
            int src_g = sg ^ (row & 7);
            gload16(A  + (size_t)(m0+row)*K + k0 + src_g*8,
                    (__bf16*)((char*)As + (32*w + 8*i)*128));
            gload16(Bt + (size_t)(n0+row)*K + k0 + src_g*8,
                    (__bf16*)((char*)Bs + (32*w + 8*i)*128));
        }
        __syncthreads();
        #pragma unroll
        for (int ks = 0; ks < 2; ++ks) {
            bf16x8 af[4], bfr[4];
            #pragma unroll
            for (int mi = 0; mi < 4; ++mi) {
                int row = wr*64 + mi*16 + lr;
                af[mi] = *(const bf16x8*)((const char*)As + ((row*128 + (lg+4*ks)*16) ^ ((row&7)<<4)));
            }
            #pragma unroll
            for (int ni = 0; ni < 4; ++ni) {
                int row = wc*64 + ni*16 + lr;
                bfr[ni] = *(const bf16x8*)((const char*)Bs + ((row*128 + (lg+4*ks)*16) ^ ((row&7)<<4)));
            }
            #pragma unroll
            for (int mi = 0; mi < 4; ++mi)
                #pragma unroll
                for (int ni = 0; ni < 4; ++ni)
                    acc[mi][ni] = __builtin_amdgcn_mfma_f32_16x16x32_bf16(af[mi], bfr[ni], acc[mi][ni], 0,0,0);
        }
    }
    #pragma unroll
    for (int mi = 0; mi < 4; ++mi) {
        #pragma unroll
        for (int ni = 0; ni < 4; ++ni) {
            #pragma unroll
            for (int r = 0; r < 4; ++r) {
                int row = m0 + wr*64 + mi*16 + lg*4 + r;
                int col = n0 + wc*64 + ni*16 + lr;
                float v = acc[mi][ni][r];
                if (EPI == 1) v += R[(size_t)row*N + col];
                if (EPI == 2) {
                    float t = 0.7978845608028654f * (v + 0.044715f*v*v*v);
                    v = 0.5f * v * (1.f + tanhf(t));
                }
                if (EPI == 2 || EPI == 3)
                    ((__bf16*)Cout)[(size_t)e*sC + (size_t)row*N + col] = (__bf16)v;
                else
                    ((float*)Cout)[(size_t)e*sC + (size_t)row*N + col] = v;
            }
        }
    }
}

// ---------------- bf16 MFMA GEMM, BM=64 x BN=128 (qkv/proj/fc2): more blocks ----------------
template<int EPI>
__global__ __launch_bounds__(256)
void gemm64_bf16_kernel(const __bf16* __restrict__ A, const __bf16* __restrict__ Bt,
                        const float* __restrict__ R, void* __restrict__ Cout,
                        int N, int K, long sA, long sB, long sC) {
    __shared__ __bf16 As[64*64];
    __shared__ __bf16 Bs[128*64];
    const int e = blockIdx.z;
    A  += (size_t)e * sA;
    Bt += (size_t)e * sB;
    const int m0 = blockIdx.y*64, n0 = blockIdx.x*128;
    const int tid = threadIdx.x;
    const int lane = tid & 63, w = tid >> 6;
    const int lr = lane & 15, lg = lane >> 4;
    const int srow8 = lane >> 3, sg = lane & 7;
    f32x4 acc[4][2] = {};
    for (int k0 = 0; k0 < K; k0 += 64) {
        __syncthreads();
        #pragma unroll
        for (int i = 0; i < 2; ++i) {
            int row = 16*w + 8*i + srow8;
            int src_g = sg ^ (row & 7);
            gload16(A + (size_t)(m0+row)*K + k0 + src_g*8,
                    (__bf16*)((char*)As + (16*w + 8*i)*128));
        }
        #pragma unroll
        for (int i = 0; i < 4; ++i) {
            int row = 32*w + 8*i + srow8;
            int src_g = sg ^ (row & 7);
            gload16(Bt + (size_t)(n0+row)*K + k0 + src_g*8,
                    (__bf16*)((char*)Bs + (32*w + 8*i)*128));
        }
        __syncthreads();
        #pragma unroll
        for (int ks = 0; ks < 2; ++ks) {
            bf16x8 af[4], bfr[2];
            #pragma unroll
            for (int mi = 0; mi < 4; ++mi) {
                int row = mi*16 + lr;
                af[mi] = *(const bf16x8*)((const char*)As + ((row*128 + (lg+4*ks)*16) ^ ((row&7)<<4)));
            }
            #pragma unroll
            for (int ni = 0; ni < 2; ++ni) {
                int row = w*32 + ni*16 + lr;
                bfr[ni] = *(const bf16x8*)((const char*)Bs + ((row*128 + (lg+4*ks)*16) ^ ((row&7)<<4)));
            }
            #pragma unroll
            for (int mi = 0; mi < 4; ++mi)
                #pragma unroll
                for (int ni = 0; ni < 2; ++ni)
                    acc[mi][ni] = __builtin_amdgcn_mfma_f32_16x16x32_bf16(af[mi], bfr[ni], acc[mi][ni], 0,0,0);
        }
    }
    #pragma unroll
    for (int mi = 0; mi < 4; ++mi) {
        #pragma unroll
        for (int ni = 0; ni < 2; ++ni) {
            #pragma unroll
            for (int r = 0; r < 4; ++r) {
                int row = m0 + mi*16 + lg*4 + r;
                int col = n0 + w*32 + ni*16 + lr;
                float v = acc[mi][ni][r];
                if (EPI == 1) v += R[(size_t)row*N + col];
                if (EPI == 2) {
                    float t = 0.7978845608028654f * (v + 0.044715f*v*v*v);
                    v = 0.5f * v * (1.f + tanhf(t));
                }
                if (EPI == 2 || EPI == 3)
                    ((__bf16*)Cout)[(size_t)e*sC + (size_t)row*N + col] = (__bf16)v;
                else
                    ((float*)Cout)[(size_t)e*sC + (size_t)row*N + col] = v;
            }
        }
    }
}

// ---------------- FUSED: attention partials ∥ weight transpose, INTERLEAVED grid ----------------
// attn blocks at bid%7==3 (bid/7 < 640); max attn bid = 7*639+3 = 4476 < 4736.
// transpose tb = bid - min(640,(bid+3)/7); bid=4735 -> 4735-640 = 4095 (max). ✓
__global__ __launch_bounds__(512)
void attn_transp_kernel(const __bf16* __restrict__ qkv, float* __restrict__ partO,
                        float* __restrict__ partML,
                        const float* __restrict__ w1, const float* __restrict__ w2,
                        __bf16* __restrict__ w1t, __bf16* __restrict__ w2t) {
    __shared__ __attribute__((aligned(16))) char smem[49152];
    const int bid = blockIdx.x;
    const bool is_attn = ((bid % 7) == 3) && (bid / 7 < ATTN_BLOCKS);

    if (!is_attn) {
        const int tb = bid - min(ATTN_BLOCKS, (bid + 3) / 7);   // 0..4095
        const int half = threadIdx.x >> 8, t256 = threadIdx.x & 255;
        float (*t)[65] = (float(*)[65])(smem + half*16640);
        const int tile = tb*2 + half;
        const float* src; __bf16* dst; int K, N, n0, k0;
        if (tile < 4096) {            // w1: [e][1024][2048] -> w1t [e][2048][1024]
            int e = tile >> 9, rem = tile & 511;
            K = HDIM; N = FDIM; n0 = (rem & 31) * 64; k0 = (rem >> 5) * 64;
            src = w1 + (size_t)e*K*N; dst = w1t + (size_t)e*K*N;
        } else {                      // w2: [e][2048][1024] -> w2t [e][1024][2048]
            int tt = tile - 4096; int e = tt >> 9, rem = tt & 511;
            K = FDIM; N = HDIM; n0 = (rem & 15) * 64; k0 = (rem >> 4) * 64;
            src = w2 + (size_t)e*K*N; dst = w2t + (size_t)e*K*N;
        }
        const int r = t256 >> 4, c4 = (t256 & 15) * 4;
        #pragma unroll
        for (int i = 0; i < 4; ++i) {
            float4 v = *(const float4*)(src + (size_t)(k0 + r + 16*i)*N + n0 + c4);
            t[r+16*i][c4+0] = v.x; t[r+16*i][c4+1] = v.y;
            t[r+16*i][c4+2] = v.z; t[r+16*i][c4+3] = v.w;
        }
        __syncthreads();
        const int rn = t256 >> 3, kc = (t256 & 7) * 8;
        #pragma unroll
        for (int i = 0; i < 2; ++i) {
            int n = rn + 32*i;
            __bf16 tmp[8];
            #pragma unroll
            for (int j = 0; j < 8; ++j) tmp[j] = (__bf16)t[kc+j][n];
            *(u32x4*)(dst + (size_t)(n0+n)*K + k0 + kc) = *(u32x4*)tmp;
        }
        return;
    }

    // ======== attention path
    __bf16* Kls = (__bf16*)smem;
    __bf16* Vls = (__bf16*)(smem + 16384);
    const int a = bid / 7;
    const int cx = a % NCHUNK;
    const int h  = a / NCHUNK;
    const int hg = h >> 2, qi = h & 3;
    const int qb = c_strip[cx];
    const int t0 = 4 * c_chunk[cx];
    const int t1 = min(qb + 1, t0 + 4);
    const int q0 = qb * 128;
    const int tid  = threadIdx.x;
    const int w    = tid >> 6;
    const int lane = tid & 63;
    const int lr   = lane & 15;
    const int lg   = lane >> 4;

    const int krow = tid >> 2, kc = (tid & 3) * 2;
    const int va = tid & 63,  dg  = tid >> 6;
    u32x4 kreg[2]; u16x8 vreg[2];

    const __bf16* kbase = qkv + hg*384 + 256;
    const __bf16* vbase = qkv + hg*384 + 320;

#define ISSUE(T) do { \
        const __bf16* kp = kbase + (size_t)((T)*128 + krow)*QKV_O + kc*8; \
        kreg[0] = *(const u32x4*)(kp); \
        kreg[1] = *(const u32x4*)(kp + 8); \
        const __bf16* vp = vbase + (size_t)((T)*128 + 2*va)*QKV_O + dg*8; \
        vreg[0] = *(const u16x8*)(vp); \
        vreg[1] = *(const u16x8*)(vp + QKV_O); \
    } while(0)

#define COMMIT() do { \
        char* Kb = (char*)Kls; \
        *(u32x4*)(Kb + ((krow*128 + (kc+0)*16) ^ ((krow&7)<<4))) = kreg[0]; \
        *(u32x4*)(Kb + ((krow*128 + (kc+1)*16) ^ ((krow&7)<<4))) = kreg[1]; \
        char* Vb = (char*)Vls; \
        _Pragma("unroll") \
        for (int j = 0; j < 8; ++j) { \
            int d = dg*8 + j; \
            u32 u = ((u32)vreg[1][j] << 16) | vreg[0][j]; \
            *(u32*)(Vb + ((d*256 + va*4) ^ ((d&7)<<4))) = u; \
        } \
    } while(0)

    const int qrow = q0 + w*16 + lr;
    const __bf16* qp = qkv + (size_t)qrow*QKV_O + hg*384 + qi*64;
    bf16x8 qfrag[2];
    #pragma unroll
    for (int ks = 0; ks < 2; ++ks) {
        bf16x8 qr = *(const bf16x8*)(qp + ks*32 + lg*8);
        #pragma unroll
        for (int j = 0; j < 8; ++j) qfrag[ks][j] = (__bf16)((float)qr[j] * 0.125f);
    }
    bf16x8 ones;
    #pragma unroll
    for (int j = 0; j < 8; ++j) ones[j] = (__bf16)1.0f;

    f32x4 oacc[4] = {};
    f32x4 lcol = {};
    float mrow[4] = {-INFINITY,-INFINITY,-INFINITY,-INFINITY};

    ISSUE(t0);
    for (int t = t0; t < t1; ++t) {
        __syncthreads();
        COMMIT();
        if (t+1 < t1) ISSUE(t+1);
        __syncthreads();

        f32x4 sacc[8] = {};
        const char* Kb = (const char*)Kls;
        #pragma unroll
        for (int f = 0; f < 8; ++f) {
            int row = lr + 16*f;
            int swz = (row & 7) << 4;
            #pragma unroll
            for (int ks = 0; ks < 2; ++ks) {
                bf16x8 kf = *(const bf16x8*)(Kb + ((row*128 + (lg*8+32*ks)*2) ^ swz));
                sacc[f] = __builtin_amdgcn_mfma_f32_16x16x32_bf16(qfrag[ks], kf, sacc[f], 0,0,0);
            }
        }
        if (t == qb) {
            #pragma unroll
            for (int f = 0; f < 8; ++f)
                #pragma unroll
                for (int r = 0; r < 4; ++r)
                    if (lr + 16*f > 16*w + 4*lg + r) sacc[f][r] = -INFINITY;
        }
        float tm[4];
        #pragma unroll
        for (int r = 0; r < 4; ++r) {
            float a2 = fmaxf(fmaxf(sacc[0][r], sacc[1][r]), fmaxf(sacc[2][r], sacc[3][r]));
            float b2 = fmaxf(fmaxf(sacc[4][r], sacc[5][r]), fmaxf(sacc[6][r], sacc[7][r]));
            tm[r] = fmaxf(a2, b2);
        }
        #pragma unroll
        for (int msk = 1; msk < 16; msk <<= 1)
            #pragma unroll
            for (int r = 0; r < 4; ++r) tm[r] = fmaxf(tm[r], __shfl_xor(tm[r], msk, 64));
        float corr[4];
        #pragma unroll
        for (int r = 0; r < 4; ++r) {
            float mn = fmaxf(mrow[r], tm[r]);
            corr[r] = exp2f((mrow[r]-mn)*LOG2E);
            mrow[r] = mn;
        }
        #pragma unroll
        for (int f = 0; f < 8; ++f)
            #pragma unroll
            for (int r = 0; r < 4; ++r)
                sacc[f][r] = exp2f((sacc[f][r]-mrow[r])*LOG2E);
        #pragma unroll
        for (int ct = 0; ct < 4; ++ct)
            #pragma unroll
            for (int r = 0; r < 4; ++r) oacc[ct][r] *= corr[r];
        #pragma unroll
        for (int r = 0; r < 4; ++r) lcol[r] *= corr[r];

        char* Pw = smem + 32768 + w*2048;
        const char* Vb = (const char*)Vls;
        #pragma unroll
        for (int half = 0; half < 2; ++half) {
            #pragma unroll
            for (int f = 0; f < 4; ++f)
                #pragma unroll
                for (int r = 0; r < 4; ++r) {
                    int row = 4*lg + r, col = lr + 16*f;
                    *(__bf16*)(Pw + ((row*128 + col*2) ^ ((row&7)<<4))) = (__bf16)sacc[4*half+f][r];
                }
            bf16x8 pa[2];
            #pragma unroll
            for (int ks = 0; ks < 2; ++ks)
                pa[ks] = *(const bf16x8*)(Pw + ((lr*128 + (lg*8+32*ks)*2) ^ ((lr&7)<<4)));
            #pragma unroll
            for (int ks = 0; ks < 2; ++ks)
                lcol = __builtin_amdgcn_mfma_f32_16x16x32_bf16(pa[ks], ones, lcol, 0,0,0);
            #pragma unroll
            for (int ct = 0; ct < 4; ++ct) {
                int row = lr + 16*ct;
                int swz = (row & 7) << 4;
                #pragma unroll
                for (int ks = 0; ks < 2; ++ks) {
                    int gks = 2*half + ks;
                    bf16x8 vf = *(const bf16x8*)(Vb + ((row*256 + (lg*8+32*gks)*2) ^ swz));
                    oacc[ct] = __builtin_amdgcn_mfma_f32_16x16x32_bf16(pa[ks], vf, oacc[ct], 0,0,0);
                }
            }
        }
    }
    const int p = h*NCHUNK + cx;
    float* po = partO + (size_t)p * (128*64);
    #pragma unroll
    for (int ct = 0; ct < 4; ++ct)
        #pragma unroll
        for (int r = 0; r < 4; ++r)
            po[(16*w + 4*lg + r)*64 + 16*ct + lr] = oacc[ct][r];
    if (lr == 0) {
        float* pm = partML + (size_t)p * 256;
        #pragma unroll
        for (int r = 0; r < 4; ++r) {
            pm[(16*w + 4*lg + r)*2    ] = mrow[r];
            pm[(16*w + 4*lg + r)*2 + 1] = lcol[r];
        }
    }
#undef ISSUE
#undef COMMIT
}

// ---------------- Flash combine ----------------
__global__ __launch_bounds__(256)
void attn_combine_kernel(const float* __restrict__ partO, const float* __restrict__ partML,
                         __bf16* __restrict__ ao) {
    const int rb = blockIdx.x, h = blockIdx.y;
    const int row0 = rb*8;
    const int qb = row0 >> 7;
    const int nc = c_nch[qb], cb = c_cbase[qb];
    const int tid = threadIdx.x;
    const int rl = tid >> 5, d2 = (tid & 31) * 2;
    const int grow = row0 + rl;
    const int srow = grow & 127;
    const int pbase = h*NCHUNK + cb;
    float mv[4], lv[4];
    float M = -INFINITY;
    for (int c = 0; c < nc; ++c) {
        const float* pm = partML + (size_t)(pbase+c)*256 + srow*2;
        mv[c] = pm[0]; lv[c] = pm[1];
        M = fmaxf(M, mv[c]);
    }
    float L = 0.f, a0 = 0.f, a1 = 0.f;
    for (int c = 0; c < nc; ++c) {
        float wc = exp2f((mv[c]-M)*LOG2E);
        L += wc * lv[c];
        const float* po = partO + (size_t)(pbase+c)*(128*64) + srow*64 + d2;
        a0 += wc * po[0];
        a1 += wc * po[1];
    }
    float inv = 1.f / L;
    __bf16 o2[2] = {(__bf16)(a0*inv), (__bf16)(a1*inv)};
    *(u32*)(ao + (size_t)grow*HDIM + h*64 + d2) = *(u32*)o2;
}

// ---------------- Fused LN2 + Router ----------------
__global__ __launch_bounds__(256)
void ln2_router_kernel(const float* __restrict__ h1, const float* __restrict__ w,
                       const float* __restrict__ b, const float* __restrict__ rw,
                       __bf16* __restrict__ x2b, int* __restrict__ expi,
                       float* __restrict__ expp) {
    const int t = blockIdx.x, tid = threadIdx.x;
    __shared__ float red[256];
    __shared__ float red8[256][8];
    const float* x = h1 + (size_t)t*HDIM;
    float xr[4];
    #pragma unroll
    for (int j = 0; j < 4; ++j) xr[j] = x[tid + 256*j];
    float s = xr[0] + xr[1] + xr[2] + xr[3];
    red[tid] = s; __syncthreads();
    for (int st = 128; st > 0; st >>= 1) { if (tid < st) red[tid] += red[tid+st]; __syncthreads(); }
    float mu = red[0] / HDIM; __syncthreads();
    float v = 0.f;
    #pragma unroll
    for (int j = 0; j < 4; ++j) { float d = xr[j]-mu; v += d*d; }
    red[tid] = v; __syncthreads();
    for (int st = 128; st > 0; st >>= 1) { if (tid < st) red[tid] += red[tid+st]; __syncthreads(); }
    float rstd = rsqrtf(red[0]/HDIM + 1e-5f);
    float part[8] = {};
    #pragma unroll
    for (int j = 0; j < 4; ++j) {
        int i = tid + 256*j;
        float o = (xr[j]-mu)*rstd*w[i] + b[i];
        x2b[(size_t)t*HDIM + i] = (__bf16)o;
        const float* wp = rw + (size_t)i*NEXP;
        #pragma unroll
        for (int e2 = 0; e2 < 8; ++e2) part[e2] += o * wp[e2];
    }
    #pragma unroll
    for (int e2 = 0; e2 < 8; ++e2) red8[tid][e2] = part[e2];
    __syncthreads();
    for (int st = 128; st > 0; st >>= 1) {
        if (tid < st)
            #pragma unroll
            for (int e2 = 0; e2 < 8; ++e2) red8[tid][e2] += red8[tid+st][e2];
        __syncthreads();
    }
    if (tid == 0) {
        float lg[8];
        #pragma unroll
        for (int e2 = 0; e2 < 8; ++e2) lg[e2] = red8[0][e2];
        int i0 = 0;
        for (int e2 = 1; e2 < 8; ++e2) if (lg[e2] > lg[i0]) i0 = e2;
        int i1 = -1;
        for (int e2 = 0; e2 < 8; ++e2) { if (e2 == i0) continue; if (i1 < 0 || lg[e2] > lg[i1]) i1 = e2; }
        float p1 = __expf(lg[i1] - lg[i0]);
        float inv = 1.f / (1.f + p1);
        expi[t*2]   = i0; expi[t*2+1] = i1;
        expp[t*2]   = inv; expp[t*2+1] = p1 * inv;
    }
}

// ---------------- Stable rank -> destination ----------------
__global__ __launch_bounds__(256)
void dst_fast_kernel(const int* __restrict__ expi, int* __restrict__ dst) {
    __shared__ int hist[256][9];
    const int tid = threadIdx.x;
    int ev[16];
    #pragma unroll
    for (int i = 0; i < 16; i += 4)
        *(int4*)(ev+i) = *(const int4*)(expi + tid*16 + i);
    int cnt[8] = {};
    #pragma unroll
    for (int i = 0; i < 16; ++i)
        #pragma unroll
        for (int e = 0; e < 8; ++e) cnt[e] += (ev[i] == e);
    #pragma unroll
    for (int e = 0; e < 8; ++e) hist[tid][e] = cnt[e];
    __syncthreads();
    const int w = tid >> 6, lane = tid & 63;
    #pragma unroll
    for (int rep = 0; rep < 2; ++rep) {
        int e = w + rep*4;
        int h0 = hist[4*lane+0][e], h1 = hist[4*lane+1][e],
            h2 = hist[4*lane+2][e], h3 = hist[4*lane+3][e];
        int s = h0+h1+h2+h3, inc = s;
        #pragma unroll
        for (int off = 1; off < 64; off <<= 1) {
            int v = __shfl_up(inc, off, 64);
            if (lane >= off) inc += v;
        }
        int excl = inc - s;
        hist[4*lane+0][e] = excl;
        hist[4*lane+1][e] = excl + h0;
        hist[4*lane+2][e] = excl + h0 + h1;
        hist[4*lane+3][e] = excl + h0 + h1 + h2;
    }
    __syncthreads();
    int run[8];
    #pragma unroll
    for (int e = 0; e < 8; ++e) run[e] = hist[tid][e];
    int out[16];
    #pragma unroll
    for (int i = 0; i < 16; ++i) {
        int e = ev[i], within = 0;
        #pragma unroll
        for (int e2 = 0; e2 < 8; ++e2)
            if (e == e2) { within = run[e2]; run[e2]++; }
        out[i] = (within < CAP) ? (e*CAP + within) : -1;
    }
    #pragma unroll
    for (int i = 0; i < 16; i += 4)
        *(int4*)(dst + tid*16 + i) = *(const int4*)(out+i);
}

// ---------------- Scatter (bf16 x2 -> bf16 xt) ----------------
__global__ void scatter_kernel(const __bf16* __restrict__ x2b, const int* __restrict__ dst,
                               __bf16* __restrict__ xt) {
    int s = blockIdx.x;
    int d = dst[s];
    if (d < 0) return;
    int t = s >> 1;
    int i = threadIdx.x;
    u32x2 v = *(const u32x2*)(x2b + (size_t)t*HDIM + i*4);
    *(u32x2*)(xt + (size_t)d*HDIM + i*4) = v;
}

// ---------------- Combine (MoE), float4 vectorized ----------------
__global__ void combine_kernel(const float* __restrict__ h1, const float* __restrict__ fc2,
                               const int* __restrict__ dst, const float* __restrict__ expp,
                               float* __restrict__ out) {
    int t = blockIdx.x;
    int d0 = dst[t*2], d1 = dst[t*2+1];
    float p0 = expp[t*2], p1 = expp[t*2+1];
    int i = threadIdx.x * 4;
    float4 v = *(const float4*)(h1 + (size_t)t*HDIM + i);
    if (d0 >= 0) {
        float4 f = *(const float4*)(fc2 + (size_t)d0*HDIM + i);
        v.x += p0*f.x; v.y += p0*f.y; v.z += p0*f.z; v.w += p0*f.w;
    }
    if (d1 >= 0) {
        float4 f = *(const float4*)(fc2 + (size_t)d1*HDIM + i);
        v.x += p1*f.x; v.y += p1*f.y; v.z += p1*f.z; v.w += p1*f.w;
    }
    *(float4*)(out + (size_t)t*HDIM + i) = v;
}

extern "C" void kernel_launch(void* const* d_in, const int* in_sizes, int n_in,
                              void* d_out, int out_size, void* d_ws, size_t ws_size,
                              hipStream_t stream) {
    const float* hidden = (const float*)d_in[0];
    const float* ln1w   = (const float*)d_in[1];
    const float* ln1b_  = (const float*)d_in[2];
    const float* ln2w   = (const float*)d_in[3];
    const float* ln2b_  = (const float*)d_in[4];
    const float* qkvW   = (const float*)d_in[5];
    const float* projW  = (const float*)d_in[6];
    const float* routW  = (const float*)d_in[7];
    const float* w1     = (const float*)d_in[8];
    const float* w2     = (const float*)d_in[9];
    float* out = (float*)d_out;

    // Arena layout (lifetime-audited; identical to round 16/17)
    char* base = (char*)d_ws;
    __bf16* w1t    = (__bf16*)(base);
    __bf16* w2t    = (__bf16*)(base + 33554432);
    __bf16* ln1b   = (__bf16*)(base);
    __bf16* qkvWb  = (__bf16*)(base + 4194304);
    char* B0 = base + 67108864;
    float*  h1   = (float*)(B0);
    __bf16* xtb  = (__bf16*)(B0 + 8388608);
    __bf16* fc1b = (__bf16*)(B0 + 18874368);
    float*  fc2  = (float*)(B0 + 39845888);
    __bf16* x2b    = (__bf16*)fc2;
    __bf16* qkvb   = (__bf16*)((char*)fc2 + 4194304);
    __bf16* aob    = (__bf16*)((char*)fc2 + 10485760);
    __bf16* projWb = (__bf16*)((char*)fc2 + 14680064);
    int*    expi = (int*)(B0 + 60817408);
    int*    dsts = (int*)(B0 + 60833792);
    float*  expp = (float*)(B0 + 60850176);
    float*  partML = (float*)xtb;
    float*  partO  = (float*)fc1b;

    // 1. prep
    prep_kernel<<<S_LEN + 768 + 512, 256, 0, stream>>>(
        hidden, ln1w, ln1b_, qkvW, projW, ln1b, projWb, qkvWb);
    // 2. QKV (BM64: 384 blocks)
    gemm64_bf16_kernel<3><<<dim3(QKV_O/128, S_LEN/64, 1), 256, 0, stream>>>(
        ln1b, qkvWb, nullptr, qkvb, QKV_O, HDIM, 0, 0, 0);
    // 3. FUSED attention ∥ transpose (interleaved grid)
    attn_transp_kernel<<<ATTN_BLOCKS + TRANSP_BLOCKS, 512, 0, stream>>>(
        qkvb, partO, partML, w1, w2, w1t, w2t);
    // 4. attention combine -> aob
    attn_combine_kernel<<<dim3(S_LEN/8, NHEAD), 256, 0, stream>>>(partO, partML, aob);
    // 5. h1 = hidden + ao @ projW^T (BM64: 256 blocks)
    gemm64_bf16_kernel<1><<<dim3(HDIM/128, S_LEN/64, 1), 256, 0, stream>>>(
        aob, projWb, hidden, h1, HDIM, HDIM, 0, 0, 0);
    // 6. LN2 + router
    ln2_router_kernel<<<S_LEN, 256, 0, stream>>>(h1, ln2w, ln2b_, routW, x2b, expi, expp);
    // 7. slots
    dst_fast_kernel<<<1, 256, 0, stream>>>(expi, dsts);
    // 8. scatter
    scatter_kernel<<<S_LEN*TOPK, 256, 0, stream>>>(x2b, dsts, xtb);
    // 9. FC1 (BM128: 640 blocks)
    gemm_bf16_kernel<2><<<dim3(FDIM/128, CAP/128, NEXP), 256, 0, stream>>>(
        xtb, w1t, nullptr, fc1b, FDIM, HDIM,
        (long)CAP*HDIM, (long)FDIM*HDIM, (long)CAP*FDIM);
    // 10. FC2 (BM64: 640 blocks)
    gemm64_bf16_kernel<0><<<dim3(HDIM/128, CAP/64, NEXP), 256, 0, stream>>>(
        fc1b, w2t, nullptr, fc2, HDIM, FDIM,
        (long)CAP*FDIM, (long)FDIM*HDIM, (long)CAP*HDIM);
    // 11. combine
    combine_kernel<<<S_LEN, 256, 0, stream>>>(h1, fc2, dsts, expp, out);
}

// Round 21
// 221.994 us; speedup vs baseline: 1.3297x; 1.0312x over previous
//
#include <hip/hip_runtime.h>
#include <hip/hip_bf16.h>
#include <stdint.h>

#define S_LEN 2048
#define HDIM  1024
#define NHEAD 16
#define NKVH  4
#define HEADD 64
#define QKV_O 1536   // NKV*(q_per_kv+2)*HD = 4*6*64
#define NEXP  8
#define TOPK  2
#define CAP   640    // ceil(2048*2/8*1.25)
#define TCAP  (NEXP*CAP)
#define FDIM  2048
#define LOG2E 1.44269504088896f
#define NCHUNK 40    // per head: sum over 16 strips of ceil((qb+1)/4)
#define ATTN_BLOCKS (NCHUNK*NHEAD)   // 640
#define FUSED_TRANSP 3072            // tiles [0,6144) -> 3072 blocks x 2 tiles
// MOD=5 interleave: attn at bid%5==3 && bid/5<640; max attn bid 5*639+3=3198 <
// 3712 total. tb = bid - min(640,(bid+2)/5) = bid - #attn<=bid -> bijective
// onto [0,3072). (bid=3711 -> (3713)/5=742 -> cap 640 -> tb=3071 max. ✓)

typedef __bf16 bf16x8 __attribute__((ext_vector_type(8)));
typedef float  f32x4  __attribute__((ext_vector_type(4)));
typedef unsigned int u32;
typedef u32 u32x4 __attribute__((ext_vector_type(4)));
typedef u32 u32x2 __attribute__((ext_vector_type(2)));
typedef unsigned short u16;
typedef u16 u16x8 __attribute__((ext_vector_type(8)));

// async global->LDS, 16B per lane; LDS dest is wave-uniform base + lane*16
__device__ __forceinline__ void gload16(const __bf16* g, __bf16* l) {
    __builtin_amdgcn_global_load_lds(
        (const __attribute__((address_space(1))) u32*)g,
        (__attribute__((address_space(3))) u32*)l, 16, 0, 0);
}

// chunk tables
__device__ __constant__ const signed char c_strip[NCHUNK] =
    {0,1,2,3, 4,4, 5,5, 6,6, 7,7, 8,8,8, 9,9,9, 10,10,10, 11,11,11,
     12,12,12,12, 13,13,13,13, 14,14,14,14, 15,15,15,15};
__device__ __constant__ const signed char c_chunk[NCHUNK] =
    {0,0,0,0, 0,1, 0,1, 0,1, 0,1, 0,1,2, 0,1,2, 0,1,2, 0,1,2,
     0,1,2,3, 0,1,2,3, 0,1,2,3, 0,1,2,3};
__device__ __constant__ const signed char c_cbase[16] = {0,1,2,3,4,6,8,10,12,15,18,21,24,28,32,36};
__device__ __constant__ const signed char c_nch[16]   = {1,1,1,1,2,2,2,2,3,3,3,3,4,4,4,4};

// ---------------- Prep: ln1(bf16) + conv(qkvW) + conv(projW) ----------------
__global__ __launch_bounds__(256)
void prep_kernel(const float* __restrict__ hidden, const float* __restrict__ ln1w,
                 const float* __restrict__ ln1bb, const float* __restrict__ qkvW,
                 const float* __restrict__ projW, __bf16* __restrict__ ln1o,
                 __bf16* __restrict__ projWb, __bf16* __restrict__ qkvWb) {
    const int b = blockIdx.x, tid = threadIdx.x;
    if (b < S_LEN) {
        __shared__ float red[256];
        const float* x = hidden + (size_t)b * HDIM;
        float xr[4];
        #pragma unroll
        for (int j = 0; j < 4; ++j) xr[j] = x[tid + 256*j];
        float s = xr[0] + xr[1] + xr[2] + xr[3];
        red[tid] = s; __syncthreads();
        for (int st = 128; st > 0; st >>= 1) { if (tid < st) red[tid] += red[tid+st]; __syncthreads(); }
        float mu = red[0] / HDIM; __syncthreads();
        float v = 0.f;
        #pragma unroll
        for (int j = 0; j < 4; ++j) { float d = xr[j]-mu; v += d*d; }
        red[tid] = v; __syncthreads();
        for (int st = 128; st > 0; st >>= 1) { if (tid < st) red[tid] += red[tid+st]; __syncthreads(); }
        float rstd = rsqrtf(red[0]/HDIM + 1e-5f);
        #pragma unroll
        for (int j = 0; j < 4; ++j) {
            int i = tid + 256*j;
            ln1o[(size_t)b*HDIM + i] = (__bf16)((xr[j]-mu)*rstd*ln1w[i] + ln1bb[i]);
        }
        return;
    }
    const float* src; __bf16* dst; int i;
    if (b < S_LEN + 768) { src = qkvW; dst = qkvWb; i = (b - S_LEN)*256 + tid; }
    else                 { src = projW; dst = projWb; i = (b - S_LEN - 768)*256 + tid; }
    const float4* s = (const float4*)src + (size_t)i*2;
    float4 a = s[0], b4 = s[1];
    __bf16 tmp[8] = {(__bf16)a.x,(__bf16)a.y,(__bf16)a.z,(__bf16)a.w,
                     (__bf16)b4.x,(__bf16)b4.y,(__bf16)b4.z,(__bf16)b4.w};
    *(u32x4*)(dst + (size_t)i*8) = *(u32x4*)tmp;
}

// ---------------- bf16 MFMA GEMM, BM=128 (fc1): C = A * Bt^T ----------------
template<int EPI>
__global__ __launch_bounds__(256)
void gemm_bf16_kernel(const __bf16* __restrict__ A, const __bf16* __restrict__ Bt,
                      const float* __restrict__ R, void* __restrict__ Cout,
                      int N, int K, long sA, long sB, long sC) {
    __shared__ __bf16 As[128*64];
    __shared__ __bf16 Bs[128*64];
    const int e = blockIdx.z;
    A  += (size_t)e * sA;
    Bt += (size_t)e * sB;
    const int m0 = blockIdx.y*128, n0 = blockIdx.x*128;
    const int tid = threadIdx.x;
    const int lane = tid & 63, w = tid >> 6;
    const int lr = lane & 15, lg = lane >> 4;
    const int wr = w >> 1, wc = w & 1;
    const int srow8 = lane >> 3, sg = lane & 7;
    f32x4 acc[4][4] = {};
    for (int k0 = 0; k0 < K; k0 += 64) {
        __syncthreads();
        #pragma unroll
        for (int i = 0; i < 4; ++i) {
            int row = 32*w + 8*i + srow8;
            int src_g = sg ^ (row & 7);
            gload16(A  + (size_t)(m0+row)*K + k0 + src_g*8,
                    (__bf16*)((char*)As + (32*w + 8*i)*128));
            gload16(Bt + (size_t)(n0+row)*K + k0 + src_g*8,
                    (__bf16*)((char*)Bs + (32*w + 8*i)*128));
        }
        __syncthreads();
        #pragma unroll
        for (int ks = 0; ks < 2; ++ks) {
            bf16x8 af[4], bfr[4];
            #pragma unroll
            for (int mi = 0; mi < 4; ++mi) {
                int row = wr*64 + mi*16 + lr;
                af[mi] = *(const bf16x8*)((const char*)As + ((row*128 + (lg+4*ks)*16) ^ ((row&7)<<4)));
            }
            #pragma unroll
            for (int ni = 0; ni < 4; ++ni) {
                int row = wc*64 + ni*16 + lr;
                bfr[ni] = *(const bf16x8*)((const char*)Bs + ((row*128 + (lg+4*ks)*16) ^ ((row&7)<<4)));
            }
            #pragma unroll
            for (int mi = 0; mi < 4; ++mi)
                #pragma unroll
                for (int ni = 0; ni < 4; ++ni)
                    acc[mi][ni] = __builtin_amdgcn_mfma_f32_16x16x32_bf16(af[mi], bfr[ni], acc[mi][ni], 0,0,0);
        }
    }
    #pragma unroll
    for (int mi = 0; mi < 4; ++mi) {
        #pragma unroll
        for (int ni = 0; ni < 4; ++ni) {
            #pragma unroll
            for (int r = 0; r < 4; ++r) {
                int row = m0 + wr*64 + mi*16 + lg*4 + r;
                int col = n0 + wc*64 + ni*16 + lr;
                float v = acc[mi][ni][r];
                if (EPI == 1) v += R[(size_t)row*N + col];
                if (EPI == 2) {
                    float t = 0.7978845608028654f * (v + 0.044715f*v*v*v);
                    v = 0.5f * v * (1.f + tanhf(t));
                }
                if (EPI == 2 || EPI == 3)
                    ((__bf16*)Cout)[(size_t)e*sC + (size_t)row*N + col] = (__bf16)v;
                else
                    ((float*)Cout)[(size_t)e*sC + (size_t)row*N + col] = v;
            }
        }
    }
}

// ---------------- bf16 MFMA GEMM, BM=64 x BN=128 (qkv/fc2) ----------------
template<int EPI>
__global__ __launch_bounds__(256)
void gemm64_bf16_kernel(const __bf16* __restrict__ A, const __bf16* __restrict__ Bt,
                        const float* __restrict__ R, void* __restrict__ Cout,
                        int N, int K, long sA, long sB, long sC) {
    __shared__ __bf16 As[64*64];
    __shared__ __bf16 Bs[128*64];
    const int e = blockIdx.z;
    A  += (size_t)e * sA;
    Bt += (size_t)e * sB;
    const int m0 = blockIdx.y*64, n0 = blockIdx.x*128;
    const int tid = threadIdx.x;
    const int lane = tid & 63, w = tid >> 6;
    const int lr = lane & 15, lg = lane >> 4;
    const int srow8 = lane >> 3, sg = lane & 7;
    f32x4 acc[4][2] = {};
    for (int k0 = 0; k0 < K; k0 += 64) {
        __syncthreads();
        #pragma unroll
        for (int i = 0; i < 2; ++i) {
            int row = 16*w + 8*i + srow8;
            int src_g = sg ^ (row & 7);
            gload16(A + (size_t)(m0+row)*K + k0 + src_g*8,
                    (__bf16*)((char*)As + (16*w + 8*i)*128));
        }
        #pragma unroll
        for (int i = 0; i < 4; ++i) {
            int row = 32*w + 8*i + srow8;
            int src_g = sg ^ (row & 7);
            gload16(Bt + (size_t)(n0+row)*K + k0 + src_g*8,
                    (__bf16*)((char*)Bs + (32*w + 8*i)*128));
        }
        __syncthreads();
        #pragma unroll
        for (int ks = 0; ks < 2; ++ks) {
            bf16x8 af[4], bfr[2];
            #pragma unroll
            for (int mi = 0; mi < 4; ++mi) {
                int row = mi*16 + lr;
                af[mi] = *(const bf16x8*)((const char*)As + ((row*128 + (lg+4*ks)*16) ^ ((row&7)<<4)));
            }
            #pragma unroll
            for (int ni = 0; ni < 2; ++ni) {
                int row = w*32 + ni*16 + lr;
                bfr[ni] = *(const bf16x8*)((const char*)Bs + ((row*128 + (lg+4*ks)*16) ^ ((row&7)<<4)));
            }
            #pragma unroll
            for (int mi = 0; mi < 4; ++mi)
                #pragma unroll
                for (int ni = 0; ni < 2; ++ni)
                    acc[mi][ni] = __builtin_amdgcn_mfma_f32_16x16x32_bf16(af[mi], bfr[ni], acc[mi][ni], 0,0,0);
        }
    }
    #pragma unroll
    for (int mi = 0; mi < 4; ++mi) {
        #pragma unroll
        for (int ni = 0; ni < 2; ++ni) {
            #pragma unroll
            for (int r = 0; r < 4; ++r) {
                int row = m0 + mi*16 + lg*4 + r;
                int col = n0 + w*32 + ni*16 + lr;
                float v = acc[mi][ni][r];
                if (EPI == 1) v += R[(size_t)row*N + col];
                if (EPI == 2) {
                    float t = 0.7978845608028654f * (v + 0.044715f*v*v*v);
                    v = 0.5f * v * (1.f + tanhf(t));
                }
                if (EPI == 2 || EPI == 3)
                    ((__bf16*)Cout)[(size_t)e*sC + (size_t)row*N + col] = (__bf16)v;
                else
                    ((float*)Cout)[(size_t)e*sC + (size_t)row*N + col] = v;
            }
        }
    }
}

// ---------------- FUSED proj (BM64) ∥ w2 transpose tiles [6144,8192) ----------------
// blocks [0,256): proj h1 = hidden + ao @ projW^T; n=bid%8, m=bid/8.
// blocks [256,2304): one 64x64 transpose tile each, tile = 6144 + (bid-256).
__global__ __launch_bounds__(256)
void proj_transp_kernel(const __bf16* __restrict__ A, const __bf16* __restrict__ Bt,
                        const float* __restrict__ R, float* __restrict__ Cout,
                        const float* __restrict__ w2, __bf16* __restrict__ w2t) {
    __shared__ __attribute__((aligned(16))) char smem[24576];
    const int bid = blockIdx.x, tid = threadIdx.x;
    if (bid >= 256) {
        // ---- transpose path (round-10 transp2 body, 1 tile)
        float (*t)[65] = (float(*)[65])smem;
        const int tile = 6144 + (bid - 256);          // in [6144,8192): all w2
        const int tt = tile - 4096;                   // w2 tile 2048..4095
        const int e = tt >> 9, rem = tt & 511;
        const int K = FDIM, N = HDIM;
        const int n0 = (rem & 15) * 64, k0 = (rem >> 4) * 64;
        const float* src = w2 + (size_t)e*K*N;
        __bf16* dst = w2t + (size_t)e*K*N;
        const int r = tid >> 4, c4 = (tid & 15) * 4;
        #pragma unroll
        for (int i = 0; i < 4; ++i) {
            float4 v = *(const float4*)(src + (size_t)(k0 + r + 16*i)*N + n0 + c4);
            t[r+16*i][c4+0] = v.x; t[r+16*i][c4+1] = v.y;
            t[r+16*i][c4+2] = v.z; t[r+16*i][c4+3] = v.w;
        }
        __syncthreads();
        const int rn = tid >> 3, kc = (tid & 7) * 8;
        #pragma unroll
        for (int i = 0; i < 2; ++i) {
            int n = rn + 32*i;
            __bf16 tmp[8];
            #pragma unroll
            for (int j = 0; j < 8; ++j) tmp[j] = (__bf16)t[kc+j][n];
            *(u32x4*)(dst + (size_t)(n0+n)*K + k0 + kc) = *(u32x4*)tmp;
        }
        return;
    }
    // ---- proj path (gemm64 EPI=1 body; N=K=HDIM)
    __bf16* As = (__bf16*)smem;                // 8KB
    __bf16* Bs = (__bf16*)(smem + 8192);       // 16KB
    const int N = HDIM, K = HDIM;
    const int m0 = (bid >> 3)*64, n0 = (bid & 7)*128;
    const int lane = tid & 63, w = tid >> 6;
    const int lr = lane & 15, lg = lane >> 4;
    const int srow8 = lane >> 3, sg = lane & 7;
    f32x4 acc[4][2] = {};
    for (int k0 = 0; k0 < K; k0 += 64) {
        __syncthreads();
        #pragma unroll
        for (int i = 0; i < 2; ++i) {
            int row = 16*w + 8*i + srow8;
            int src_g = sg ^ (row & 7);
            gload16(A + (size_t)(m0+row)*K + k0 + src_g*8,
                    (__bf16*)((char*)As + (16*w + 8*i)*128));
        }
        #pragma unroll
        for (int i = 0; i < 4; ++i) {
            int row = 32*w + 8*i + srow8;
            int src_g = sg ^ (row & 7);
            gload16(Bt + (size_t)(n0+row)*K + k0 + src_g*8,
                    (__bf16*)((char*)Bs + (32*w + 8*i)*128));
        }
        __syncthreads();
        #pragma unroll
        for (int ks = 0; ks < 2; ++ks) {
            bf16x8 af[4], bfr[2];
            #pragma unroll
            for (int mi = 0; mi < 4; ++mi) {
                int row = mi*16 + lr;
                af[mi] = *(const bf16x8*)((const char*)As + ((row*128 + (lg+4*ks)*16) ^ ((row&7)<<4)));
            }
            #pragma unroll
            for (int ni = 0; ni < 2; ++ni) {
                int row = w*32 + ni*16 + lr;
                bfr[ni] = *(const bf16x8*)((const char*)Bs + ((row*128 + (lg+4*ks)*16) ^ ((row&7)<<4)));
            }
            #pragma unroll
            for (int mi = 0; mi < 4; ++mi)
                #pragma unroll
                for (int ni = 0; ni < 2; ++ni)
                    acc[mi][ni] = __builtin_amdgcn_mfma_f32_16x16x32_bf16(af[mi], bfr[ni], acc[mi][ni], 0,0,0);
        }
    }
    #pragma unroll
    for (int mi = 0; mi < 4; ++mi) {
        #pragma unroll
        for (int ni = 0; ni < 2; ++ni) {
            #pragma unroll
            for (int r = 0; r < 4; ++r) {
                int row = m0 + mi*16 + lg*4 + r;
                int col = n0 + w*32 + ni*16 + lr;
                Cout[(size_t)row*N + col] = acc[mi][ni][r] + R[(size_t)row*N + col];
            }
        }
    }
}

// ---------------- FUSED: attention ∥ transpose tiles [0,6144), MOD=5 interleave ----------------
__global__ __launch_bounds__(512)
void attn_transp_kernel(const __bf16* __restrict__ qkv, float* __restrict__ partO,
                        float* __restrict__ partML,
                        const float* __restrict__ w1, const float* __restrict__ w2,
                        __bf16* __restrict__ w1t, __bf16* __restrict__ w2t) {
    __shared__ __attribute__((aligned(16))) char smem[49152];
    const int bid = blockIdx.x;
    const bool is_attn = ((bid % 5) == 3) && (bid / 5 < ATTN_BLOCKS);

    if (!is_attn) {
        const int tb = bid - min(ATTN_BLOCKS, (bid + 2) / 5);   // 0..3071 (bijective)
        const int half = threadIdx.x >> 8, t256 = threadIdx.x & 255;
        float (*t)[65] = (float(*)[65])(smem + half*16640);
        const int tile = tb*2 + half;                            // 0..6143
        const float* src; __bf16* dst; int K, N, n0, k0;
        if (tile < 4096) {            // w1: [e][1024][2048] -> w1t [e][2048][1024]
            int e = tile >> 9, rem = tile & 511;
            K = HDIM; N = FDIM; n0 = (rem & 31) * 64; k0 = (rem >> 5) * 64;
            src = w1 + (size_t)e*K*N; dst = w1t + (size_t)e*K*N;
        } else {                      // w2 tiles 0..2047
            int tt = tile - 4096; int e = tt >> 9, rem = tt & 511;
            K = FDIM; N = HDIM; n0 = (rem & 15) * 64; k0 = (rem >> 4) * 64;
            src = w2 + (size_t)e*K*N; dst = w2t + (size_t)e*K*N;
        }
        const int r = t256 >> 4, c4 = (t256 & 15) * 4;
        #pragma unroll
        for (int i = 0; i < 4; ++i) {
            float4 v = *(const float4*)(src + (size_t)(k0 + r + 16*i)*N + n0 + c4);
            t[r+16*i][c4+0] = v.x; t[r+16*i][c4+1] = v.y;
            t[r+16*i][c4+2] = v.z; t[r+16*i][c4+3] = v.w;
        }
        __syncthreads();
        const int rn = t256 >> 3, kc = (t256 & 7) * 8;
        #pragma unroll
        for (int i = 0; i < 2; ++i) {
            int n = rn + 32*i;
            __bf16 tmp[8];
            #pragma unroll
            for (int j = 0; j < 8; ++j) tmp[j] = (__bf16)t[kc+j][n];
            *(u32x4*)(dst + (size_t)(n0+n)*K + k0 + kc) = *(u32x4*)tmp;
        }
        return;
    }

    // ======== attention path
    __bf16* Kls = (__bf16*)smem;
    __bf16* Vls = (__bf16*)(smem + 16384);
    const int a = bid / 5;
    const int cx = a % NCHUNK;
    const int h  = a / NCHUNK;
    const int hg = h >> 2, qi = h & 3;
    const int qb = c_strip[cx];
    const int t0 = 4 * c_chunk[cx];
    const int t1 = min(qb + 1, t0 + 4);
    const int q0 = qb * 128;
    const int tid  = threadIdx.x;
    const int w    = tid >> 6;
    const int lane = tid & 63;
    const int lr   = lane & 15;
    const int lg   = lane >> 4;

    const int krow = tid >> 2, kc = (tid & 3) * 2;
    const int va = tid & 63,  dg  = tid >> 6;
    u32x4 kreg[2]; u16x8 vreg[2];

    const __bf16* kbase = qkv + hg*384 + 256;
    const __bf16* vbase = qkv + hg*384 + 320;

#define ISSUE(T) do { \
        const __bf16* kp = kbase + (size_t)((T)*128 + krow)*QKV_O + kc*8; \
        kreg[0] = *(const u32x4*)(kp); \
        kreg[1] = *(const u32x4*)(kp + 8); \
        const __bf16* vp = vbase + (size_t)((T)*128 + 2*va)*QKV_O + dg*8; \
        vreg[0] = *(const u16x8*)(vp); \
        vreg[1] = *(const u16x8*)(vp + QKV_O); \
    } while(0)

#define COMMIT() do { \
        char* Kb = (char*)Kls; \
        *(u32x4*)(Kb + ((krow*128 + (kc+0)*16) ^ ((krow&7)<<4))) = kreg[0]; \
        *(u32x4*)(Kb + ((krow*128 + (kc+1)*16) ^ ((krow&7)<<4))) = kreg[1]; \
        char* Vb = (char*)Vls; \
        _Pragma("unroll") \
        for (int j = 0; j < 8; ++j) { \
            int d = dg*8 + j; \
            u32 u = ((u32)vreg[1][j] << 16) | vreg[0][j]; \
            *(u32*)(Vb + ((d*256 + va*4) ^ ((d&7)<<4))) = u; \
        } \
    } while(0)

    const int qrow = q0 + w*16 + lr;
    const __bf16* qp = qkv + (size_t)qrow*QKV_O + hg*384 + qi*64;
    bf16x8 qfrag[2];
    #pragma unroll
    for (int ks = 0; ks < 2; ++ks) {
        bf16x8 qr = *(const bf16x8*)(qp + ks*32 + lg*8);
        #pragma unroll
        for (int j = 0; j < 8; ++j) qfrag[ks][j] = (__bf16)((float)qr[j] * 0.125f);
    }
    bf16x8 ones;
    #pragma unroll
    for (int j = 0; j < 8; ++j) ones[j] = (__bf16)1.0f;

    f32x4 oacc[4] = {};
    f32x4 lcol = {};
    float mrow[4] = {-INFINITY,-INFINITY,-INFINITY,-INFINITY};

    ISSUE(t0);
    for (int t = t0; t < t1; ++t) {
        __syncthreads();
        COMMIT();
        if (t+1 < t1) ISSUE(t+1);
        __syncthreads();

        f32x4 sacc[8] = {};
        const char* Kb = (const char*)Kls;
        #pragma unroll
        for (int f = 0; f < 8; ++f) {
            int row = lr + 16*f;
            int swz = (row & 7) << 4;
            #pragma unroll
            for (int ks = 0; ks < 2; ++ks) {
                bf16x8 kf = *(const bf16x8*)(Kb + ((row*128 + (lg*8+32*ks)*2) ^ swz));
                sacc[f] = __builtin_amdgcn_mfma_f32_16x16x32_bf16(qfrag[ks], kf, sacc[f], 0,0,0);
            }
        }
        if (t == qb) {
            #pragma unroll
            for (int f = 0; f < 8; ++f)
                #pragma unroll
                for (int r = 0; r < 4; ++r)
                    if (lr + 16*f > 16*w + 4*lg + r) sacc[f][r] = -INFINITY;
        }
        float tm[4];
        #pragma unroll
        for (int r = 0; r < 4; ++r) {
            float a2 = fmaxf(fmaxf(sacc[0][r], sacc[1][r]), fmaxf(sacc[2][r], sacc[3][r]));
            float b2 = fmaxf(fmaxf(sacc[4][r], sacc[5][r]), fmaxf(sacc[6][r], sacc[7][r]));
            tm[r] = fmaxf(a2, b2);
        }
        #pragma unroll
        for (int msk = 1; msk < 16; msk <<= 1)
            #pragma unroll
            for (int r = 0; r < 4; ++r) tm[r] = fmaxf(tm[r], __shfl_xor(tm[r], msk, 64));
        float corr[4];
        #pragma unroll
        for (int r = 0; r < 4; ++r) {
            float mn = fmaxf(mrow[r], tm[r]);
            corr[r] = exp2f((mrow[r]-mn)*LOG2E);
            mrow[r] = mn;
        }
        #pragma unroll
        for (int f = 0; f < 8; ++f)
            #pragma unroll
            for (int r = 0; r < 4; ++r)
                sacc[f][r] = exp2f((sacc[f][r]-mrow[r])*LOG2E);
        #pragma unroll
        for (int ct = 0; ct < 4; ++ct)
            #pragma unroll
            for (int r = 0; r < 4; ++r) oacc[ct][r] *= corr[r];
        #pragma unroll
        for (int r = 0; r < 4; ++r) lcol[r] *= corr[r];

        char* Pw = smem + 32768 + w*2048;
        const char* Vb = (const char*)Vls;
        #pragma unroll
        for (int half = 0; half < 2; ++half) {
            #pragma unroll
            for (int f = 0; f < 4; ++f)
                #pragma unroll
                for (int r = 0; r < 4; ++r) {
                    int row = 4*lg + r, col = lr + 16*f;
                    *(__bf16*)(Pw + ((row*128 + col*2) ^ ((row&7)<<4))) = (__bf16)sacc[4*half+f][r];
                }
            bf16x8 pa[2];
            #pragma unroll
            for (int ks = 0; ks < 2; ++ks)
                pa[ks] = *(const bf16x8*)(Pw + ((lr*128 + (lg*8+32*ks)*2) ^ ((lr&7)<<4)));
            #pragma unroll
            for (int ks = 0; ks < 2; ++ks)
                lcol = __builtin_amdgcn_mfma_f32_16x16x32_bf16(pa[ks], ones, lcol, 0,0,0);
            #pragma unroll
            for (int ct = 0; ct < 4; ++ct) {
                int row = lr + 16*ct;
                int swz = (row & 7) << 4;
                #pragma unroll
                for (int ks = 0; ks < 2; ++ks) {
                    int gks = 2*half + ks;
                    bf16x8 vf = *(const bf16x8*)(Vb + ((row*256 + (lg*8+32*gks)*2) ^ swz));
                    oacc[ct] = __builtin_amdgcn_mfma_f32_16x16x32_bf16(pa[ks], vf, oacc[ct], 0,0,0);
                }
            }
        }
    }
    const int p = h*NCHUNK + cx;
    float* po = partO + (size_t)p * (128*64);
    #pragma unroll
    for (int ct = 0; ct < 4; ++ct)
        #pragma unroll
        for (int r = 0; r < 4; ++r)
            po[(16*w + 4*lg + r)*64 + 16*ct + lr] = oacc[ct][r];
    if (lr == 0) {
        float* pm = partML + (size_t)p * 256;
        #pragma unroll
        for (int r = 0; r < 4; ++r) {
            pm[(16*w + 4*lg + r)*2    ] = mrow[r];
            pm[(16*w + 4*lg + r)*2 + 1] = lcol[r];
        }
    }
#undef ISSUE
#undef COMMIT
}

// ---------------- Flash combine ----------------
__global__ __launch_bounds__(256)
void attn_combine_kernel(const float* __restrict__ partO, const float* __restrict__ partML,
                         __bf16* __restrict__ ao) {
    const int rb = blockIdx.x, h = blockIdx.y;
    const int row0 = rb*8;
    const int qb = row0 >> 7;
    const int nc = c_nch[qb], cb = c_cbase[qb];
    const int tid = threadIdx.x;
    const int rl = tid >> 5, d2 = (tid & 31) * 2;
    const int grow = row0 + rl;
    const int srow = grow & 127;
    const int pbase = h*NCHUNK + cb;
    float mv[4], lv[4];
    float M = -INFINITY;
    for (int c = 0; c < nc; ++c) {
        const float* pm = partML + (size_t)(pbase+c)*256 + srow*2;
        mv[c] = pm[0]; lv[c] = pm[1];
        M = fmaxf(M, mv[c]);
    }
    float L = 0.f, a0 = 0.f, a1 = 0.f;
    for (int c = 0; c < nc; ++c) {
        float wc = exp2f((mv[c]-M)*LOG2E);
        L += wc * lv[c];
        const float* po = partO + (size_t)(pbase+c)*(128*64) + srow*64 + d2;
        a0 += wc * po[0];
        a1 += wc * po[1];
    }
    float inv = 1.f / L;
    __bf16 o2[2] = {(__bf16)(a0*inv), (__bf16)(a1*inv)};
    *(u32*)(ao + (size_t)grow*HDIM + h*64 + d2) = *(u32*)o2;
}

// ---------------- Fused LN2 + Router ----------------
__global__ __launch_bounds__(256)
void ln2_router_kernel(const float* __restrict__ h1, const float* __restrict__ w,
                       const float* __restrict__ b, const float* __restrict__ rw,
                       __bf16* __restrict__ x2b, int* __restrict__ expi,
                       float* __restrict__ expp) {
    const int t = blockIdx.x, tid = threadIdx.x;
    __shared__ float red[256];
    __shared__ float red8[256][8];
    const float* x = h1 + (size_t)t*HDIM;
    float xr[4];
    #pragma unroll
    for (int j = 0; j < 4; ++j) xr[j] = x[tid + 256*j];
    float s = xr[0] + xr[1] + xr[2] + xr[3];
    red[tid] = s; __syncthreads();
    for (int st = 128; st > 0; st >>= 1) { if (tid < st) red[tid] += red[tid+st]; __syncthreads(); }
    float mu = red[0] / HDIM; __syncthreads();
    float v = 0.f;
    #pragma unroll
    for (int j = 0; j < 4; ++j) { float d = xr[j]-mu; v += d*d; }
    red[tid] = v; __syncthreads();
    for (int st = 128; st > 0; st >>= 1) { if (tid < st) red[tid] += red[tid+st]; __syncthreads(); }
    float rstd = rsqrtf(red[0]/HDIM + 1e-5f);
    float part[8] = {};
    #pragma unroll
    for (int j = 0; j < 4; ++j) {
        int i = tid + 256*j;
        float o = (xr[j]-mu)*rstd*w[i] + b[i];
        x2b[(size_t)t*HDIM + i] = (__bf16)o;
        const float* wp = rw + (size_t)i*NEXP;
        #pragma unroll
        for (int e2 = 0; e2 < 8; ++e2) part[e2] += o * wp[e2];
    }
    #pragma unroll
    for (int e2 = 0; e2 < 8; ++e2) red8[tid][e2] = part[e2];
    __syncthreads();
    for (int st = 128; st > 0; st >>= 1) {
        if (tid < st)
            #pragma unroll
            for (int e2 = 0; e2 < 8; ++e2) red8[tid][e2] += red8[tid+st][e2];
        __syncthreads();
    }
    if (tid == 0) {
        float lg[8];
        #pragma unroll
        for (int e2 = 0; e2 < 8; ++e2) lg[e2] = red8[0][e2];
        int i0 = 0;
        for (int e2 = 1; e2 < 8; ++e2) if (lg[e2] > lg[i0]) i0 = e2;
        int i1 = -1;
        for (int e2 = 0; e2 < 8; ++e2) { if (e2 == i0) continue; if (i1 < 0 || lg[e2] > lg[i1]) i1 = e2; }
        float p1 = __expf(lg[i1] - lg[i0]);
        float inv = 1.f / (1.f + p1);
        expi[t*2]   = i0; expi[t*2+1] = i1;
        expp[t*2]   = inv; expp[t*2+1] = p1 * inv;
    }
}

// ---------------- Stable rank -> destination ----------------
__global__ __launch_bounds__(256)
void dst_fast_kernel(const int* __restrict__ expi, int* __restrict__ dst) {
    __shared__ int hist[256][9];
    const int tid = threadIdx.x;
    int ev[16];
    #pragma unroll
    for (int i = 0; i < 16; i += 4)
        *(int4*)(ev+i) = *(const int4*)(expi + tid*16 + i);
    int cnt[8] = {};
    #pragma unroll
    for (int i = 0; i < 16; ++i)
        #pragma unroll
        for (int e = 0; e < 8; ++e) cnt[e] += (ev[i] == e);
    #pragma unroll
    for (int e = 0; e < 8; ++e) hist[tid][e] = cnt[e];
    __syncthreads();
    const int w = tid >> 6, lane = tid & 63;
    #pragma unroll
    for (int rep = 0; rep < 2; ++rep) {
        int e = w + rep*4;
        int h0 = hist[4*lane+0][e], h1 = hist[4*lane+1][e],
            h2 = hist[4*lane+2][e], h3 = hist[4*lane+3][e];
        int s = h0+h1+h2+h3, inc = s;
        #pragma unroll
        for (int off = 1; off < 64; off <<= 1) {
            int v = __shfl_up(inc, off, 64);
            if (lane >= off) inc += v;
        }
        int excl = inc - s;
        hist[4*lane+0][e] = excl;
        hist[4*lane+1][e] = excl + h0;
        hist[4*lane+2][e] = excl + h0 + h1;
        hist[4*lane+3][e] = excl + h0 + h1 + h2;
    }
    __syncthreads();
    int run[8];
    #pragma unroll
    for (int e = 0; e < 8; ++e) run[e] = hist[tid][e];
    int out[16];
    #pragma unroll
    for (int i = 0; i < 16; ++i) {
        int e = ev[i], within = 0;
        #pragma unroll
        for (int e2 = 0; e2 < 8; ++e2)
            if (e == e2) { within = run[e2]; run[e2]++; }
        out[i] = (within < CAP) ? (e*CAP + within) : -1;
    }
    #pragma unroll
    for (int i = 0; i < 16; i += 4)
        *(int4*)(dst + tid*16 + i) = *(const int4*)(out+i);
}

// ---------------- Scatter (bf16 x2 -> bf16 xt) ----------------
__global__ void scatter_kernel(const __bf16* __restrict__ x2b, const int* __restrict__ dst,
                               __bf16* __restrict__ xt) {
    int s = blockIdx.x;
    int d = dst[s];
    if (d < 0) return;
    int t = s >> 1;
    int i = threadIdx.x;
    u32x2 v = *(const u32x2*)(x2b + (size_t)t*HDIM + i*4);
    *(u32x2*)(xt + (size_t)d*HDIM + i*4) = v;
}

// ---------------- Combine (MoE), float4 vectorized ----------------
__global__ void combine_kernel(const float* __restrict__ h1, const float* __restrict__ fc2,
                               const int* __restrict__ dst, const float* __restrict__ expp,
                               float* __restrict__ out) {
    int t = blockIdx.x;
    int d0 = dst[t*2], d1 = dst[t*2+1];
    float p0 = expp[t*2], p1 = expp[t*2+1];
    int i = threadIdx.x * 4;
    float4 v = *(const float4*)(h1 + (size_t)t*HDIM + i);
    if (d0 >= 0) {
        float4 f = *(const float4*)(fc2 + (size_t)d0*HDIM + i);
        v.x += p0*f.x; v.y += p0*f.y; v.z += p0*f.z; v.w += p0*f.w;
    }
    if (d1 >= 0) {
        float4 f = *(const float4*)(fc2 + (size_t)d1*HDIM + i);
        v.x += p1*f.x; v.y += p1*f.y; v.z += p1*f.z; v.w += p1*f.w;
    }
    *(float4*)(out + (size_t)t*HDIM + i) = v;
}

extern "C" void kernel_launch(void* const* d_in, const int* in_sizes, int n_in,
                              void* d_out, int out_size, void* d_ws, size_t ws_size,
                              hipStream_t stream) {
    const float* hidden = (const float*)d_in[0];
    const float* ln1w   = (const float*)d_in[1];
    const float* ln1b_  = (const float*)d_in[2];
    const float* ln2w   = (const float*)d_in[3];
    const float* ln2b_  = (const float*)d_in[4];
    const float* qkvW   = (const float*)d_in[5];
    const float* projW  = (const float*)d_in[6];
    const float* routW  = (const float*)d_in[7];
    const float* w1     = (const float*)d_in[8];
    const float* w2     = (const float*)d_in[9];
    float* out = (float*)d_out;

    // Arena layout (lifetime-audited; identical to rounds 16/17/20).
    // w2t second half [tiles 6144..8191] is written in step 5 (proj-fused),
    // read first in step 10 (fc2) — no earlier reader. ✓
    char* base = (char*)d_ws;
    __bf16* w1t    = (__bf16*)(base);
    __bf16* w2t    = (__bf16*)(base + 33554432);
    __bf16* ln1b   = (__bf16*)(base);
    __bf16* qkvWb  = (__bf16*)(base + 4194304);
    char* B0 = base + 67108864;
    float*  h1   = (float*)(B0);
    __bf16* xtb  = (__bf16*)(B0 + 8388608);
    __bf16* fc1b = (__bf16*)(B0 + 18874368);
    float*  fc2  = (float*)(B0 + 39845888);
    __bf16* x2b    = (__bf16*)fc2;
    __bf16* qkvb   = (__bf16*)((char*)fc2 + 4194304);
    __bf16* aob    = (__bf16*)((char*)fc2 + 10485760);
    __bf16* projWb = (__bf16*)((char*)fc2 + 14680064);
    int*    expi = (int*)(B0 + 60817408);
    int*    dsts = (int*)(B0 + 60833792);
    float*  expp = (float*)(B0 + 60850176);
    float*  partML = (float*)xtb;
    float*  partO  = (float*)fc1b;

    // 1. prep
    prep_kernel<<<S_LEN + 768 + 512, 256, 0, stream>>>(
        hidden, ln1w, ln1b_, qkvW, projW, ln1b, projWb, qkvWb);
    // 2. QKV (BM64: 384 blocks)
    gemm64_bf16_kernel<3><<<dim3(QKV_O/128, S_LEN/64, 1), 256, 0, stream>>>(
        ln1b, qkvWb, nullptr, qkvb, QKV_O, HDIM, 0, 0, 0);
    // 3. FUSED attention ∥ transpose tiles [0,6144) (MOD=5 interleave)
    attn_transp_kernel<<<ATTN_BLOCKS + FUSED_TRANSP, 512, 0, stream>>>(
        qkvb, partO, partML, w1, w2, w1t, w2t);
    // 4. attention combine -> aob
    attn_combine_kernel<<<dim3(S_LEN/8, NHEAD), 256, 0, stream>>>(partO, partML, aob);
    // 5. FUSED proj ∥ transpose tiles [6144,8192)
    proj_transp_kernel<<<256 + 2048, 256, 0, stream>>>(
        aob, projWb, hidden, h1, w2, w2t);
    // 6. LN2 + router
    ln2_router_kernel<<<S_LEN, 256, 0, stream>>>(h1, ln2w, ln2b_, routW, x2b, expi, expp);
    // 7. slots
    dst_fast_kernel<<<1, 256, 0, stream>>>(expi, dsts);
    // 8. scatter
    scatter_kernel<<<S_LEN*TOPK, 256, 0, stream>>>(x2b, dsts, xtb);
    // 9. FC1 (BM128: 640 blocks)
    gemm_bf16_kernel<2><<<dim3(FDIM/128, CAP/128, NEXP), 256, 0, stream>>>(
        xtb, w1t, nullptr, fc1b, FDIM, HDIM,
        (long)CAP*HDIM, (long)FDIM*HDIM, (long)CAP*FDIM);
    // 10. FC2 (BM64: 640 blocks)
    gemm64_bf16_kernel<0><<<dim3(HDIM/128, CAP/64, NEXP), 256, 0, stream>>>(
        fc1b, w2t, nullptr, fc2, HDIM, FDIM,
        (long)CAP*FDIM, (long)FDIM*HDIM, (long)CAP*HDIM);
    // 11. combine
    combine_kernel<<<S_LEN, 256, 0, stream>>>(h1, fc2, dsts, expp, out);
}

// Round 22
// 220.854 us; speedup vs baseline: 1.3366x; 1.0052x over previous
//
#include <hip/hip_runtime.h>
#include <hip/hip_bf16.h>
#include <stdint.h>

#define S_LEN 2048
#define HDIM  1024
#define NHEAD 16
#define NKVH  4
#define HEADD 64
#define QKV_O 1536   // NKV*(q_per_kv+2)*HD = 4*6*64
#define NEXP  8
#define TOPK  2
#define CAP   640    // ceil(2048*2/8*1.25)
#define TCAP  (NEXP*CAP)
#define FDIM  2048
#define LOG2E 1.44269504088896f
#define NCHUNK 40
#define ATTN_BLOCKS (NCHUNK*NHEAD)   // 640
#define ATTN_TRANSP 2560             // tiles [0,4096)+[5120,6144) -> 2560 blocks x 2
// attn-fused MOD=5: attn at bid%5==3 && bid/5<640 (max 3198 < 3200).
// tb = bid - min(640,(bid+2)/5) bijective onto [0,2560). tile0 = tb*2+half;
// tile = tile0<4096 ? tile0 : tile0+1024  -> [0,4096) u [5120,6144).
// qkv-fused MOD=3: qkv at bid%3==1 && bid/3<384 (max 1150 < 1408).
// tb = bid - min(384,(bid+2)/3) bijective onto [0,1024); tile = 4096+tb.

typedef __bf16 bf16x8 __attribute__((ext_vector_type(8)));
typedef float  f32x4  __attribute__((ext_vector_type(4)));
typedef unsigned int u32;
typedef u32 u32x4 __attribute__((ext_vector_type(4)));
typedef u32 u32x2 __attribute__((ext_vector_type(2)));
typedef unsigned short u16;
typedef u16 u16x8 __attribute__((ext_vector_type(8)));

// async global->LDS, 16B per lane; LDS dest is wave-uniform base + lane*16
__device__ __forceinline__ void gload16(const __bf16* g, __bf16* l) {
    __builtin_amdgcn_global_load_lds(
        (const __attribute__((address_space(1))) u32*)g,
        (__attribute__((address_space(3))) u32*)l, 16, 0, 0);
}

__device__ __constant__ const signed char c_strip[NCHUNK] =
    {0,1,2,3, 4,4, 5,5, 6,6, 7,7, 8,8,8, 9,9,9, 10,10,10, 11,11,11,
     12,12,12,12, 13,13,13,13, 14,14,14,14, 15,15,15,15};
__device__ __constant__ const signed char c_chunk[NCHUNK] =
    {0,0,0,0, 0,1, 0,1, 0,1, 0,1, 0,1,2, 0,1,2, 0,1,2, 0,1,2,
     0,1,2,3, 0,1,2,3, 0,1,2,3, 0,1,2,3};
__device__ __constant__ const signed char c_cbase[16] = {0,1,2,3,4,6,8,10,12,15,18,21,24,28,32,36};
__device__ __constant__ const signed char c_nch[16]   = {1,1,1,1,2,2,2,2,3,3,3,3,4,4,4,4};

// ---------------- 64x64 transpose tile body (shared by fused kernels) ----------------
__device__ __forceinline__ void transp_tile(const float* __restrict__ w1,
                                            const float* __restrict__ w2,
                                            __bf16* __restrict__ w1t,
                                            __bf16* __restrict__ w2t,
                                            int tile, int tid, char* smem) {
    float (*t)[65] = (float(*)[65])smem;
    const float* src; __bf16* dst; int K, N, n0, k0;
    if (tile < 4096) {            // w1: [e][1024][2048] -> w1t [e][2048][1024]
        int e = tile >> 9, rem = tile & 511;
        K = HDIM; N = FDIM; n0 = (rem & 31) * 64; k0 = (rem >> 5) * 64;
        src = w1 + (size_t)e*K*N; dst = w1t + (size_t)e*K*N;
    } else {                      // w2: [e][2048][1024] -> w2t [e][1024][2048]
        int tt = tile - 4096; int e = tt >> 9, rem = tt & 511;
        K = FDIM; N = HDIM; n0 = (rem & 15) * 64; k0 = (rem >> 4) * 64;
        src = w2 + (size_t)e*K*N; dst = w2t + (size_t)e*K*N;
    }
    const int r = tid >> 4, c4 = (tid & 15) * 4;
    #pragma unroll
    for (int i = 0; i < 4; ++i) {
        float4 v = *(const float4*)(src + (size_t)(k0 + r + 16*i)*N + n0 + c4);
        t[r+16*i][c4+0] = v.x; t[r+16*i][c4+1] = v.y;
        t[r+16*i][c4+2] = v.z; t[r+16*i][c4+3] = v.w;
    }
    __syncthreads();
    const int rn = tid >> 3, kc = (tid & 7) * 8;
    #pragma unroll
    for (int i = 0; i < 2; ++i) {
        int n = rn + 32*i;
        __bf16 tmp[8];
        #pragma unroll
        for (int j = 0; j < 8; ++j) tmp[j] = (__bf16)t[kc+j][n];
        *(u32x4*)(dst + (size_t)(n0+n)*K + k0 + kc) = *(u32x4*)tmp;
    }
}

// ---------------- Prep: ln1(bf16) + conv(qkvW) + conv(projW) ----------------
__global__ __launch_bounds__(256)
void prep_kernel(const float* __restrict__ hidden, const float* __restrict__ ln1w,
                 const float* __restrict__ ln1bb, const float* __restrict__ qkvW,
                 const float* __restrict__ projW, __bf16* __restrict__ ln1o,
                 __bf16* __restrict__ projWb, __bf16* __restrict__ qkvWb) {
    const int b = blockIdx.x, tid = threadIdx.x;
    if (b < S_LEN) {
        __shared__ float red[256];
        const float* x = hidden + (size_t)b * HDIM;
        float xr[4];
        #pragma unroll
        for (int j = 0; j < 4; ++j) xr[j] = x[tid + 256*j];
        float s = xr[0] + xr[1] + xr[2] + xr[3];
        red[tid] = s; __syncthreads();
        for (int st = 128; st > 0; st >>= 1) { if (tid < st) red[tid] += red[tid+st]; __syncthreads(); }
        float mu = red[0] / HDIM; __syncthreads();
        float v = 0.f;
        #pragma unroll
        for (int j = 0; j < 4; ++j) { float d = xr[j]-mu; v += d*d; }
        red[tid] = v; __syncthreads();
        for (int st = 128; st > 0; st >>= 1) { if (tid < st) red[tid] += red[tid+st]; __syncthreads(); }
        float rstd = rsqrtf(red[0]/HDIM + 1e-5f);
        #pragma unroll
        for (int j = 0; j < 4; ++j) {
            int i = tid + 256*j;
            ln1o[(size_t)b*HDIM + i] = (__bf16)((xr[j]-mu)*rstd*ln1w[i] + ln1bb[i]);
        }
        return;
    }
    const float* src; __bf16* dst; int i;
    if (b < S_LEN + 768) { src = qkvW; dst = qkvWb; i = (b - S_LEN)*256 + tid; }
    else                 { src = projW; dst = projWb; i = (b - S_LEN - 768)*256 + tid; }
    const float4* s = (const float4*)src + (size_t)i*2;
    float4 a = s[0], b4 = s[1];
    __bf16 tmp[8] = {(__bf16)a.x,(__bf16)a.y,(__bf16)a.z,(__bf16)a.w,
                     (__bf16)b4.x,(__bf16)b4.y,(__bf16)b4.z,(__bf16)b4.w};
    *(u32x4*)(dst + (size_t)i*8) = *(u32x4*)tmp;
}

// ---------------- bf16 MFMA GEMM, BM=128 (fc1) ----------------
template<int EPI>
__global__ __launch_bounds__(256)
void gemm_bf16_kernel(const __bf16* __restrict__ A, const __bf16* __restrict__ Bt,
                      const float* __restrict__ R, void* __restrict__ Cout,
                      int N, int K, long sA, long sB, long sC) {
    __shared__ __bf16 As[128*64];
    __shared__ __bf16 Bs[128*64];
    const int e = blockIdx.z;
    A  += (size_t)e * sA;
    Bt += (size_t)e * sB;
    const int m0 = blockIdx.y*128, n0 = blockIdx.x*128;
    const int tid = threadIdx.x;
    const int lane = tid & 63, w = tid >> 6;
    const int lr = lane & 15, lg = lane >> 4;
    const int wr = w >> 1, wc = w & 1;
    const int srow8 = lane >> 3, sg = lane & 7;
    f32x4 acc[4][4] = {};
    for (int k0 = 0; k0 < K; k0 += 64) {
        __syncthreads();
        #pragma unroll
        for (int i = 0; i < 4; ++i) {
            int row = 32*w + 8*i + srow8;
            int src_g = sg ^ (row & 7);
            gload16(A  + (size_t)(m0+row)*K + k0 + src_g*8,
                    (__bf16*)((char*)As + (32*w + 8*i)*128));
            gload16(Bt + (size_t)(n0+row)*K + k0 + src_g*8,
                    (__bf16*)((char*)Bs + (32*w + 8*i)*128));
        }
        __syncthreads();
        #pragma unroll
        for (int ks = 0; ks < 2; ++ks) {
            bf16x8 af[4], bfr[4];
            #pragma unroll
            for (int mi = 0; mi < 4; ++mi) {
                int row = wr*64 + mi*16 + lr;
                af[mi] = *(const bf16x8*)((const char*)As + ((row*128 + (lg+4*ks)*16) ^ ((row&7)<<4)));
            }
            #pragma unroll
            for (int ni = 0; ni < 4; ++ni) {
                int row = wc*64 + ni*16 + lr;
                bfr[ni] = *(const bf16x8*)((const char*)Bs + ((row*128 + (lg+4*ks)*16) ^ ((row&7)<<4)));
            }
            #pragma unroll
            for (int mi = 0; mi < 4; ++mi)
                #pragma unroll
                for (int ni = 0; ni < 4; ++ni)
                    acc[mi][ni] = __builtin_amdgcn_mfma_f32_16x16x32_bf16(af[mi], bfr[ni], acc[mi][ni], 0,0,0);
        }
    }
    #pragma unroll
    for (int mi = 0; mi < 4; ++mi) {
        #pragma unroll
        for (int ni = 0; ni < 4; ++ni) {
            #pragma unroll
            for (int r = 0; r < 4; ++r) {
                int row = m0 + wr*64 + mi*16 + lg*4 + r;
                int col = n0 + wc*64 + ni*16 + lr;
                float v = acc[mi][ni][r];
                if (EPI == 1) v += R[(size_t)row*N + col];
                if (EPI == 2) {
                    float t = 0.7978845608028654f * (v + 0.044715f*v*v*v);
                    v = 0.5f * v * (1.f + tanhf(t));
                }
                if (EPI == 2 || EPI == 3)
                    ((__bf16*)Cout)[(size_t)e*sC + (size_t)row*N + col] = (__bf16)v;
                else
                    ((float*)Cout)[(size_t)e*sC + (size_t)row*N + col] = v;
            }
        }
    }
}

// ---------------- bf16 MFMA GEMM, BM=64 x BN=128 (fc2) ----------------
template<int EPI>
__global__ __launch_bounds__(256)
void gemm64_bf16_kernel(const __bf16* __restrict__ A, const __bf16* __restrict__ Bt,
                        const float* __restrict__ R, void* __restrict__ Cout,
                        int N, int K, long sA, long sB, long sC) {
    __shared__ __bf16 As[64*64];
    __shared__ __bf16 Bs[128*64];
    const int e = blockIdx.z;
    A  += (size_t)e * sA;
    Bt += (size_t)e * sB;
    const int m0 = blockIdx.y*64, n0 = blockIdx.x*128;
    const int tid = threadIdx.x;
    const int lane = tid & 63, w = tid >> 6;
    const int lr = lane & 15, lg = lane >> 4;
    const int srow8 = lane >> 3, sg = lane & 7;
    f32x4 acc[4][2] = {};
    for (int k0 = 0; k0 < K; k0 += 64) {
        __syncthreads();
        #pragma unroll
        for (int i = 0; i < 2; ++i) {
            int row = 16*w + 8*i + srow8;
            int src_g = sg ^ (row & 7);
            gload16(A + (size_t)(m0+row)*K + k0 + src_g*8,
                    (__bf16*)((char*)As + (16*w + 8*i)*128));
        }
        #pragma unroll
        for (int i = 0; i < 4; ++i) {
            int row = 32*w + 8*i + srow8;
            int src_g = sg ^ (row & 7);
            gload16(Bt + (size_t)(n0+row)*K + k0 + src_g*8,
                    (__bf16*)((char*)Bs + (32*w + 8*i)*128));
        }
        __syncthreads();
        #pragma unroll
        for (int ks = 0; ks < 2; ++ks) {
            bf16x8 af[4], bfr[2];
            #pragma unroll
            for (int mi = 0; mi < 4; ++mi) {
                int row = mi*16 + lr;
                af[mi] = *(const bf16x8*)((const char*)As + ((row*128 + (lg+4*ks)*16) ^ ((row&7)<<4)));
            }
            #pragma unroll
            for (int ni = 0; ni < 2; ++ni) {
                int row = w*32 + ni*16 + lr;
                bfr[ni] = *(const bf16x8*)((const char*)Bs + ((row*128 + (lg+4*ks)*16) ^ ((row&7)<<4)));
            }
            #pragma unroll
            for (int mi = 0; mi < 4; ++mi)
                #pragma unroll
                for (int ni = 0; ni < 2; ++ni)
                    acc[mi][ni] = __builtin_amdgcn_mfma_f32_16x16x32_bf16(af[mi], bfr[ni], acc[mi][ni], 0,0,0);
        }
    }
    #pragma unroll
    for (int mi = 0; mi < 4; ++mi) {
        #pragma unroll
        for (int ni = 0; ni < 2; ++ni) {
            #pragma unroll
            for (int r = 0; r < 4; ++r) {
                int row = m0 + mi*16 + lg*4 + r;
                int col = n0 + w*32 + ni*16 + lr;
                float v = acc[mi][ni][r];
                if (EPI == 1) v += R[(size_t)row*N + col];
                if (EPI == 2) {
                    float t = 0.7978845608028654f * (v + 0.044715f*v*v*v);
                    v = 0.5f * v * (1.f + tanhf(t));
                }
                if (EPI == 2 || EPI == 3)
                    ((__bf16*)Cout)[(size_t)e*sC + (size_t)row*N + col] = (__bf16)v;
                else
                    ((float*)Cout)[(size_t)e*sC + (size_t)row*N + col] = v;
            }
        }
    }
}

// ---------------- FUSED qkv (BM64) ∥ w2 transpose tiles [4096,5120) ----------------
// qkv at bid%3==1 && bid/3<384; transpose tb = bid - min(384,(bid+2)/3).
__global__ __launch_bounds__(256)
void qkv_transp_kernel(const __bf16* __restrict__ A, const __bf16* __restrict__ Bt,
                       __bf16* __restrict__ Cout,
                       const float* __restrict__ w1, const float* __restrict__ w2,
                       __bf16* __restrict__ w1t, __bf16* __restrict__ w2t) {
    __shared__ __attribute__((aligned(16))) char smem[24576];
    const int bid = blockIdx.x, tid = threadIdx.x;
    const bool is_gemm = ((bid % 3) == 1) && (bid / 3 < 384);
    if (!is_gemm) {
        const int tb = bid - min(384, (bid + 2) / 3);   // 0..1023 (bijective)
        transp_tile(w1, w2, w1t, w2t, 4096 + tb, tid, smem);
        return;
    }
    // qkv GEMM: g = bid/3; n-tile = g%12, m-tile = g/12. N=QKV_O, K=HDIM.
    __bf16* As = (__bf16*)smem;
    __bf16* Bs = (__bf16*)(smem + 8192);
    const int g = bid / 3;
    const int N = QKV_O, K = HDIM;
    const int m0 = (g / 12)*64, n0 = (g % 12)*128;
    const int lane = tid & 63, w = tid >> 6;
    const int lr = lane & 15, lg = lane >> 4;
    const int srow8 = lane >> 3, sg = lane & 7;
    f32x4 acc[4][2] = {};
    for (int k0 = 0; k0 < K; k0 += 64) {
        __syncthreads();
        #pragma unroll
        for (int i = 0; i < 2; ++i) {
            int row = 16*w + 8*i + srow8;
            int src_g = sg ^ (row & 7);
            gload16(A + (size_t)(m0+row)*K + k0 + src_g*8,
                    (__bf16*)((char*)As + (16*w + 8*i)*128));
        }
        #pragma unroll
        for (int i = 0; i < 4; ++i) {
            int row = 32*w + 8*i + srow8;
            int src_g = sg ^ (row & 7);
            gload16(Bt + (size_t)(n0+row)*K + k0 + src_g*8,
                    (__bf16*)((char*)Bs + (32*w + 8*i)*128));
        }
        __syncthreads();
        #pragma unroll
        for (int ks = 0; ks < 2; ++ks) {
            bf16x8 af[4], bfr[2];
            #pragma unroll
            for (int mi = 0; mi < 4; ++mi) {
                int row = mi*16 + lr;
                af[mi] = *(const bf16x8*)((const char*)As + ((row*128 + (lg+4*ks)*16) ^ ((row&7)<<4)));
            }
            #pragma unroll
            for (int ni = 0; ni < 2; ++ni) {
                int row = w*32 + ni*16 + lr;
                bfr[ni] = *(const bf16x8*)((const char*)Bs + ((row*128 + (lg+4*ks)*16) ^ ((row&7)<<4)));
            }
            #pragma unroll
            for (int mi = 0; mi < 4; ++mi)
                #pragma unroll
                for (int ni = 0; ni < 2; ++ni)
                    acc[mi][ni] = __builtin_amdgcn_mfma_f32_16x16x32_bf16(af[mi], bfr[ni], acc[mi][ni], 0,0,0);
        }
    }
    #pragma unroll
    for (int mi = 0; mi < 4; ++mi)
        #pragma unroll
        for (int ni = 0; ni < 2; ++ni)
            #pragma unroll
            for (int r = 0; r < 4; ++r) {
                int row = m0 + mi*16 + lg*4 + r;
                int col = n0 + w*32 + ni*16 + lr;
                Cout[(size_t)row*N + col] = (__bf16)acc[mi][ni][r];
            }
}

// ---------------- FUSED proj (BM64) ∥ w2 transpose tiles [6144,8192) ----------------
__global__ __launch_bounds__(256)
void proj_transp_kernel(const __bf16* __restrict__ A, const __bf16* __restrict__ Bt,
                        const float* __restrict__ R, float* __restrict__ Cout,
                        const float* __restrict__ w1, const float* __restrict__ w2,
                        __bf16* __restrict__ w1t, __bf16* __restrict__ w2t) {
    __shared__ __attribute__((aligned(16))) char smem[24576];
    const int bid = blockIdx.x, tid = threadIdx.x;
    if (bid >= 256) {
        transp_tile(w1, w2, w1t, w2t, 6144 + (bid - 256), tid, smem);
        return;
    }
    // proj GEMM (gemm64 EPI=1 body; N=K=HDIM)
    __bf16* As = (__bf16*)smem;
    __bf16* Bs = (__bf16*)(smem + 8192);
    const int N = HDIM, K = HDIM;
    const int m0 = (bid >> 3)*64, n0 = (bid & 7)*128;
    const int lane = tid & 63, w = tid >> 6;
    const int lr = lane & 15, lg = lane >> 4;
    const int srow8 = lane >> 3, sg = lane & 7;
    f32x4 acc[4][2] = {};
    for (int k0 = 0; k0 < K; k0 += 64) {
        __syncthreads();
        #pragma unroll
        for (int i = 0; i < 2; ++i) {
            int row = 16*w + 8*i + srow8;
            int src_g = sg ^ (row & 7);
            gload16(A + (size_t)(m0+row)*K + k0 + src_g*8,
                    (__bf16*)((char*)As + (16*w + 8*i)*128));
        }
        #pragma unroll
        for (int i = 0; i < 4; ++i) {
            int row = 32*w + 8*i + srow8;
            int src_g = sg ^ (row & 7);
            gload16(Bt + (size_t)(n0+row)*K + k0 + src_g*8,
                    (__bf16*)((char*)Bs + (32*w + 8*i)*128));
        }
        __syncthreads();
        #pragma unroll
        for (int ks = 0; ks < 2; ++ks) {
            bf16x8 af[4], bfr[2];
            #pragma unroll
            for (int mi = 0; mi < 4; ++mi) {
                int row = mi*16 + lr;
                af[mi] = *(const bf16x8*)((const char*)As + ((row*128 + (lg+4*ks)*16) ^ ((row&7)<<4)));
            }
            #pragma unroll
            for (int ni = 0; ni < 2; ++ni) {
                int row = w*32 + ni*16 + lr;
                bfr[ni] = *(const bf16x8*)((const char*)Bs + ((row*128 + (lg+4*ks)*16) ^ ((row&7)<<4)));
            }
            #pragma unroll
            for (int mi = 0; mi < 4; ++mi)
                #pragma unroll
                for (int ni = 0; ni < 2; ++ni)
                    acc[mi][ni] = __builtin_amdgcn_mfma_f32_16x16x32_bf16(af[mi], bfr[ni], acc[mi][ni], 0,0,0);
        }
    }
    #pragma unroll
    for (int mi = 0; mi < 4; ++mi)
        #pragma unroll
        for (int ni = 0; ni < 2; ++ni)
            #pragma unroll
            for (int r = 0; r < 4; ++r) {
                int row = m0 + mi*16 + lg*4 + r;
                int col = n0 + w*32 + ni*16 + lr;
                Cout[(size_t)row*N + col] = acc[mi][ni][r] + R[(size_t)row*N + col];
            }
}

// ---------------- FUSED: attention ∥ transpose tiles [0,4096)u[5120,6144) ----------------
__global__ __launch_bounds__(512)
void attn_transp_kernel(const __bf16* __restrict__ qkv, float* __restrict__ partO,
                        float* __restrict__ partML,
                        const float* __restrict__ w1, const float* __restrict__ w2,
                        __bf16* __restrict__ w1t, __bf16* __restrict__ w2t) {
    __shared__ __attribute__((aligned(16))) char smem[49152];
    const int bid = blockIdx.x;
    const bool is_attn = ((bid % 5) == 3) && (bid / 5 < ATTN_BLOCKS);

    if (!is_attn) {
        const int tb = bid - min(ATTN_BLOCKS, (bid + 2) / 5);   // 0..2559 (bijective)
        const int half = threadIdx.x >> 8, t256 = threadIdx.x & 255;
        int tile0 = tb*2 + half;                                 // 0..5119
        int tile = (tile0 < 4096) ? tile0 : tile0 + 1024;        // skip [4096,5120)
        transp_tile(w1, w2, w1t, w2t, tile, t256, smem + half*16640);
        return;
    }

    // ======== attention path
    __bf16* Kls = (__bf16*)smem;
    __bf16* Vls = (__bf16*)(smem + 16384);
    const int a = bid / 5;
    const int cx = a % NCHUNK;
    const int h  = a / NCHUNK;
    const int hg = h >> 2, qi = h & 3;
    const int qb = c_strip[cx];
    const int t0 = 4 * c_chunk[cx];
    const int t1 = min(qb + 1, t0 + 4);
    const int q0 = qb * 128;
    const int tid  = threadIdx.x;
    const int w    = tid >> 6;
    const int lane = tid & 63;
    const int lr   = lane & 15;
    const int lg   = lane >> 4;

    const int krow = tid >> 2, kc = (tid & 3) * 2;
    const int va = tid & 63,  dg  = tid >> 6;
    u32x4 kreg[2]; u16x8 vreg[2];

    const __bf16* kbase = qkv + hg*384 + 256;
    const __bf16* vbase = qkv + hg*384 + 320;

#define ISSUE(T) do { \
        const __bf16* kp = kbase + (size_t)((T)*128 + krow)*QKV_O + kc*8; \
        kreg[0] = *(const u32x4*)(kp); \
        kreg[1] = *(const u32x4*)(kp + 8); \
        const __bf16* vp = vbase + (size_t)((T)*128 + 2*va)*QKV_O + dg*8; \
        vreg[0] = *(const u16x8*)(vp); \
        vreg[1] = *(const u16x8*)(vp + QKV_O); \
    } while(0)

#define COMMIT() do { \
        char* Kb = (char*)Kls; \
        *(u32x4*)(Kb + ((krow*128 + (kc+0)*16) ^ ((krow&7)<<4))) = kreg[0]; \
        *(u32x4*)(Kb + ((krow*128 + (kc+1)*16) ^ ((krow&7)<<4))) = kreg[1]; \
        char* Vb = (char*)Vls; \
        _Pragma("unroll") \
        for (int j = 0; j < 8; ++j) { \
            int d = dg*8 + j; \
            u32 u = ((u32)vreg[1][j] << 16) | vreg[0][j]; \
            *(u32*)(Vb + ((d*256 + va*4) ^ ((d&7)<<4))) = u; \
        } \
    } while(0)

    const int qrow = q0 + w*16 + lr;
    const __bf16* qp = qkv + (size_t)qrow*QKV_O + hg*384 + qi*64;
    bf16x8 qfrag[2];
    #pragma unroll
    for (int ks = 0; ks < 2; ++ks) {
        bf16x8 qr = *(const bf16x8*)(qp + ks*32 + lg*8);
        #pragma unroll
        for (int j = 0; j < 8; ++j) qfrag[ks][j] = (__bf16)((float)qr[j] * 0.125f);
    }
    bf16x8 ones;
    #pragma unroll
    for (int j = 0; j < 8; ++j) ones[j] = (__bf16)1.0f;

    f32x4 oacc[4] = {};
    f32x4 lcol = {};
    float mrow[4] = {-INFINITY,-INFINITY,-INFINITY,-INFINITY};

    ISSUE(t0);
    for (int t = t0; t < t1; ++t) {
        __syncthreads();
        COMMIT();
        if (t+1 < t1) ISSUE(t+1);
        __syncthreads();

        f32x4 sacc[8] = {};
        const char* Kb = (const char*)Kls;
        #pragma unroll
        for (int f = 0; f < 8; ++f) {
            int row = lr + 16*f;
            int swz = (row & 7) << 4;
            #pragma unroll
            for (int ks = 0; ks < 2; ++ks) {
                bf16x8 kf = *(const bf16x8*)(Kb + ((row*128 + (lg*8+32*ks)*2) ^ swz));
                sacc[f] = __builtin_amdgcn_mfma_f32_16x16x32_bf16(qfrag[ks], kf, sacc[f], 0,0,0);
            }
        }
        if (t == qb) {
            #pragma unroll
            for (int f = 0; f < 8; ++f)
                #pragma unroll
                for (int r = 0; r < 4; ++r)
                    if (lr + 16*f > 16*w + 4*lg + r) sacc[f][r] = -INFINITY;
        }
        float tm[4];
        #pragma unroll
        for (int r = 0; r < 4; ++r) {
            float a2 = fmaxf(fmaxf(sacc[0][r], sacc[1][r]), fmaxf(sacc[2][r], sacc[3][r]));
            float b2 = fmaxf(fmaxf(sacc[4][r], sacc[5][r]), fmaxf(sacc[6][r], sacc[7][r]));
            tm[r] = fmaxf(a2, b2);
        }
        #pragma unroll
        for (int msk = 1; msk < 16; msk <<= 1)
            #pragma unroll
            for (int r = 0; r < 4; ++r) tm[r] = fmaxf(tm[r], __shfl_xor(tm[r], msk, 64));
        float corr[4];
        #pragma unroll
        for (int r = 0; r < 4; ++r) {
            float mn = fmaxf(mrow[r], tm[r]);
            corr[r] = exp2f((mrow[r]-mn)*LOG2E);
            mrow[r] = mn;
        }
        #pragma unroll
        for (int f = 0; f < 8; ++f)
            #pragma unroll
            for (int r = 0; r < 4; ++r)
                sacc[f][r] = exp2f((sacc[f][r]-mrow[r])*LOG2E);
        #pragma unroll
        for (int ct = 0; ct < 4; ++ct)
            #pragma unroll
            for (int r = 0; r < 4; ++r) oacc[ct][r] *= corr[r];
        #pragma unroll
        for (int r = 0; r < 4; ++r) lcol[r] *= corr[r];

        char* Pw = smem + 32768 + w*2048;
        const char* Vb = (const char*)Vls;
        #pragma unroll
        for (int half = 0; half < 2; ++half) {
            #pragma unroll
            for (int f = 0; f < 4; ++f)
                #pragma unroll
                for (int r = 0; r < 4; ++r) {
                    int row = 4*lg + r, col = lr + 16*f;
                    *(__bf16*)(Pw + ((row*128 + col*2) ^ ((row&7)<<4))) = (__bf16)sacc[4*half+f][r];
                }
            bf16x8 pa[2];
            #pragma unroll
            for (int ks = 0; ks < 2; ++ks)
                pa[ks] = *(const bf16x8*)(Pw + ((lr*128 + (lg*8+32*ks)*2) ^ ((lr&7)<<4)));
            #pragma unroll
            for (int ks = 0; ks < 2; ++ks)
                lcol = __builtin_amdgcn_mfma_f32_16x16x32_bf16(pa[ks], ones, lcol, 0,0,0);
            #pragma unroll
            for (int ct = 0; ct < 4; ++ct) {
                int row = lr + 16*ct;
                int swz = (row & 7) << 4;
                #pragma unroll
                for (int ks = 0; ks < 2; ++ks) {
                    int gks = 2*half + ks;
                    bf16x8 vf = *(const bf16x8*)(Vb + ((row*256 + (lg*8+32*gks)*2) ^ swz));
                    oacc[ct] = __builtin_amdgcn_mfma_f32_16x16x32_bf16(pa[ks], vf, oacc[ct], 0,0,0);
                }
            }
        }
    }
    const int p = h*NCHUNK + cx;
    float* po = partO + (size_t)p * (128*64);
    #pragma unroll
    for (int ct = 0; ct < 4; ++ct)
        #pragma unroll
        for (int r = 0; r < 4; ++r)
            po[(16*w + 4*lg + r)*64 + 16*ct + lr] = oacc[ct][r];
    if (lr == 0) {
        float* pm = partML + (size_t)p * 256;
        #pragma unroll
        for (int r = 0; r < 4; ++r) {
            pm[(16*w + 4*lg + r)*2    ] = mrow[r];
            pm[(16*w + 4*lg + r)*2 + 1] = lcol[r];
        }
    }
#undef ISSUE
#undef COMMIT
}

// ---------------- Flash combine ----------------
__global__ __launch_bounds__(256)
void attn_combine_kernel(const float* __restrict__ partO, const float* __restrict__ partML,
                         __bf16* __restrict__ ao) {
    const int rb = blockIdx.x, h = blockIdx.y;
    const int row0 = rb*8;
    const int qb = row0 >> 7;
    const int nc = c_nch[qb], cb = c_cbase[qb];
    const int tid = threadIdx.x;
    const int rl = tid >> 5, d2 = (tid & 31) * 2;
    const int grow = row0 + rl;
    const int srow = grow & 127;
    const int pbase = h*NCHUNK + cb;
    float mv[4], lv[4];
    float M = -INFINITY;
    for (int c = 0; c < nc; ++c) {
        const float* pm = partML + (size_t)(pbase+c)*256 + srow*2;
        mv[c] = pm[0]; lv[c] = pm[1];
        M = fmaxf(M, mv[c]);
    }
    float L = 0.f, a0 = 0.f, a1 = 0.f;
    for (int c = 0; c < nc; ++c) {
        float wc = exp2f((mv[c]-M)*LOG2E);
        L += wc * lv[c];
        const float* po = partO + (size_t)(pbase+c)*(128*64) + srow*64 + d2;
        a0 += wc * po[0];
        a1 += wc * po[1];
    }
    float inv = 1.f / L;
    __bf16 o2[2] = {(__bf16)(a0*inv), (__bf16)(a1*inv)};
    *(u32*)(ao + (size_t)grow*HDIM + h*64 + d2) = *(u32*)o2;
}

// ---------------- Fused LN2 + Router ----------------
__global__ __launch_bounds__(256)
void ln2_router_kernel(const float* __restrict__ h1, const float* __restrict__ w,
                       const float* __restrict__ b, const float* __restrict__ rw,
                       __bf16* __restrict__ x2b, int* __restrict__ expi,
                       float* __restrict__ expp) {
    const int t = blockIdx.x, tid = threadIdx.x;
    __shared__ float red[256];
    __shared__ float red8[256][8];
    const float* x = h1 + (size_t)t*HDIM;
    float xr[4];
    #pragma unroll
    for (int j = 0; j < 4; ++j) xr[j] = x[tid + 256*j];
    float s = xr[0] + xr[1] + xr[2] + xr[3];
    red[tid] = s; __syncthreads();
    for (int st = 128; st > 0; st >>= 1) { if (tid < st) red[tid] += red[tid+st]; __syncthreads(); }
    float mu = red[0] / HDIM; __syncthreads();
    float v = 0.f;
    #pragma unroll
    for (int j = 0; j < 4; ++j) { float d = xr[j]-mu; v += d*d; }
    red[tid] = v; __syncthreads();
    for (int st = 128; st > 0; st >>= 1) { if (tid < st) red[tid] += red[tid+st]; __syncthreads(); }
    float rstd = rsqrtf(red[0]/HDIM + 1e-5f);
    float part[8] = {};
    #pragma unroll
    for (int j = 0; j < 4; ++j) {
        int i = tid + 256*j;
        float o = (xr[j]-mu)*rstd*w[i] + b[i];
        x2b[(size_t)t*HDIM + i] = (__bf16)o;
        const float* wp = rw + (size_t)i*NEXP;
        #pragma unroll
        for (int e2 = 0; e2 < 8; ++e2) part[e2] += o * wp[e2];
    }
    #pragma unroll
    for (int e2 = 0; e2 < 8; ++e2) red8[tid][e2] = part[e2];
    __syncthreads();
    for (int st = 128; st > 0; st >>= 1) {
        if (tid < st)
            #pragma unroll
            for (int e2 = 0; e2 < 8; ++e2) red8[tid][e2] += red8[tid+st][e2];
        __syncthreads();
    }
    if (tid == 0) {
        float lg[8];
        #pragma unroll
        for (int e2 = 0; e2 < 8; ++e2) lg[e2] = red8[0][e2];
        int i0 = 0;
        for (int e2 = 1; e2 < 8; ++e2) if (lg[e2] > lg[i0]) i0 = e2;
        int i1 = -1;
        for (int e2 = 0; e2 < 8; ++e2) { if (e2 == i0) continue; if (i1 < 0 || lg[e2] > lg[i1]) i1 = e2; }
        float p1 = __expf(lg[i1] - lg[i0]);
        float inv = 1.f / (1.f + p1);
        expi[t*2]   = i0; expi[t*2+1] = i1;
        expp[t*2]   = inv; expp[t*2+1] = p1 * inv;
    }
}

// ---------------- Stable rank -> destination ----------------
__global__ __launch_bounds__(256)
void dst_fast_kernel(const int* __restrict__ expi, int* __restrict__ dst) {
    __shared__ int hist[256][9];
    const int tid = threadIdx.x;
    int ev[16];
    #pragma unroll
    for (int i = 0; i < 16; i += 4)
        *(int4*)(ev+i) = *(const int4*)(expi + tid*16 + i);
    int cnt[8] = {};
    #pragma unroll
    for (int i = 0; i < 16; ++i)
        #pragma unroll
        for (int e = 0; e < 8; ++e) cnt[e] += (ev[i] == e);
    #pragma unroll
    for (int e = 0; e < 8; ++e) hist[tid][e] = cnt[e];
    __syncthreads();
    const int w = tid >> 6, lane = tid & 63;
    #pragma unroll
    for (int rep = 0; rep < 2; ++rep) {
        int e = w + rep*4;
        int h0 = hist[4*lane+0][e], h1 = hist[4*lane+1][e],
            h2 = hist[4*lane+2][e], h3 = hist[4*lane+3][e];
        int s = h0+h1+h2+h3, inc = s;
        #pragma unroll
        for (int off = 1; off < 64; off <<= 1) {
            int v = __shfl_up(inc, off, 64);
            if (lane >= off) inc += v;
        }
        int excl = inc - s;
        hist[4*lane+0][e] = excl;
        hist[4*lane+1][e] = excl + h0;
        hist[4*lane+2][e] = excl + h0 + h1;
        hist[4*lane+3][e] = excl + h0 + h1 + h2;
    }
    __syncthreads();
    int run[8];
    #pragma unroll
    for (int e = 0; e < 8; ++e) run[e] = hist[tid][e];
    int out[16];
    #pragma unroll
    for (int i = 0; i < 16; ++i) {
        int e = ev[i], within = 0;
        #pragma unroll
        for (int e2 = 0; e2 < 8; ++e2)
            if (e == e2) { within = run[e2]; run[e2]++; }
        out[i] = (within < CAP) ? (e*CAP + within) : -1;
    }
    #pragma unroll
    for (int i = 0; i < 16; i += 4)
        *(int4*)(dst + tid*16 + i) = *(const int4*)(out+i);
}

// ---------------- Scatter (bf16 x2 -> bf16 xt) ----------------
__global__ void scatter_kernel(const __bf16* __restrict__ x2b, const int* __restrict__ dst,
                               __bf16* __restrict__ xt) {
    int s = blockIdx.x;
    int d = dst[s];
    if (d < 0) return;
    int t = s >> 1;
    int i = threadIdx.x;
    u32x2 v = *(const u32x2*)(x2b + (size_t)t*HDIM + i*4);
    *(u32x2*)(xt + (size_t)d*HDIM + i*4) = v;
}

// ---------------- Combine (MoE), bf16 fc2 ----------------
__global__ void combine_kernel(const float* __restrict__ h1, const __bf16* __restrict__ fc2b,
                               const int* __restrict__ dst, const float* __restrict__ expp,
                               float* __restrict__ out) {
    int t = blockIdx.x;
    int d0 = dst[t*2], d1 = dst[t*2+1];
    float p0 = expp[t*2], p1 = expp[t*2+1];
    int i = threadIdx.x * 4;
    float4 v = *(const float4*)(h1 + (size_t)t*HDIM + i);
    if (d0 >= 0) {
        u16x8 f; *(u32x2*)&f = *(const u32x2*)(fc2b + (size_t)d0*HDIM + i);
        const __bf16* fb = (const __bf16*)&f;
        v.x += p0*(float)fb[0]; v.y += p0*(float)fb[1];
        v.z += p0*(float)fb[2]; v.w += p0*(float)fb[3];
    }
    if (d1 >= 0) {
        u16x8 f; *(u32x2*)&f = *(const u32x2*)(fc2b + (size_t)d1*HDIM + i);
        const __bf16* fb = (const __bf16*)&f;
        v.x += p1*(float)fb[0]; v.y += p1*(float)fb[1];
        v.z += p1*(float)fb[2]; v.w += p1*(float)fb[3];
    }
    *(float4*)(out + (size_t)t*HDIM + i) = v;
}

extern "C" void kernel_launch(void* const* d_in, const int* in_sizes, int n_in,
                              void* d_out, int out_size, void* d_ws, size_t ws_size,
                              hipStream_t stream) {
    const float* hidden = (const float*)d_in[0];
    const float* ln1w   = (const float*)d_in[1];
    const float* ln1b_  = (const float*)d_in[2];
    const float* ln2w   = (const float*)d_in[3];
    const float* ln2b_  = (const float*)d_in[4];
    const float* qkvW   = (const float*)d_in[5];
    const float* projW  = (const float*)d_in[6];
    const float* routW  = (const float*)d_in[7];
    const float* w1     = (const float*)d_in[8];
    const float* w2     = (const float*)d_in[9];
    float* out = (float*)d_out;

    // Arena (lifetimes audited rounds 16-21). w2t writers: qkv-fused (tiles
    // 4096-5119 -> w2t experts 0-1), attn-fused (5120-6143 -> experts 2-3),
    // proj-fused (6144-8191 -> experts 4-7); first reader fc2 (step 10). ✓
    // qkv-fused reads ln1b/qkvWb which alias w1t ONLY ([0,7M)); its transpose
    // writes are w2t-only (base+32M..) -> no clobber. ✓
    char* base = (char*)d_ws;
    __bf16* w1t    = (__bf16*)(base);
    __bf16* w2t    = (__bf16*)(base + 33554432);
    __bf16* ln1b   = (__bf16*)(base);
    __bf16* qkvWb  = (__bf16*)(base + 4194304);
    char* B0 = base + 67108864;
    float*  h1   = (float*)(B0);
    __bf16* xtb  = (__bf16*)(B0 + 8388608);
    __bf16* fc1b = (__bf16*)(B0 + 18874368);
    __bf16* fc2b = (__bf16*)(B0 + 39845888);          // bf16 now (10.5MB)
    __bf16* x2b    = (__bf16*)((char*)fc2b + 10485760);  // moved clear of fc2b
    __bf16* qkvb   = (__bf16*)((char*)fc2b + 14680064);
    __bf16* aob    = (__bf16*)(B0 + 60817408 + 65536);   // 4MB after small bufs
    __bf16* projWb = (__bf16*)((char*)aob + 4194304);    // 2MB
    int*    expi = (int*)(B0 + 60817408);
    int*    dsts = (int*)(B0 + 60833792);
    float*  expp = (float*)(B0 + 60850176);
    float*  partML = (float*)xtb;
    float*  partO  = (float*)fc1b;

    // 1. prep
    prep_kernel<<<S_LEN + 768 + 512, 256, 0, stream>>>(
        hidden, ln1w, ln1b_, qkvW, projW, ln1b, projWb, qkvWb);
    // 2. FUSED QKV ∥ w2 transpose tiles [4096,5120)
    qkv_transp_kernel<<<384 + 1024, 256, 0, stream>>>(
        ln1b, qkvWb, qkvb, w1, w2, w1t, w2t);
    // 3. FUSED attention ∥ transpose tiles [0,4096)u[5120,6144)
    attn_transp_kernel<<<ATTN_BLOCKS + ATTN_TRANSP, 512, 0, stream>>>(
        qkvb, partO, partML, w1, w2, w1t, w2t);
    // 4. attention combine -> aob
    attn_combine_kernel<<<dim3(S_LEN/8, NHEAD), 256, 0, stream>>>(partO, partML, aob);
    // 5. FUSED proj ∥ transpose tiles [6144,8192)
    proj_transp_kernel<<<256 + 2048, 256, 0, stream>>>(
        aob, projWb, hidden, h1, w1, w2, w1t, w2t);
    // 6. LN2 + router
    ln2_router_kernel<<<S_LEN, 256, 0, stream>>>(h1, ln2w, ln2b_, routW, x2b, expi, expp);
    // 7. slots
    dst_fast_kernel<<<1, 256, 0, stream>>>(expi, dsts);
    // 8. scatter
    scatter_kernel<<<S_LEN*TOPK, 256, 0, stream>>>(x2b, dsts, xtb);
    // 9. FC1 (BM128: 640 blocks)
    gemm_bf16_kernel<2><<<dim3(FDIM/128, CAP/128, NEXP), 256, 0, stream>>>(
        xtb, w1t, nullptr, fc1b, FDIM, HDIM,
        (long)CAP*HDIM, (long)FDIM*HDIM, (long)CAP*FDIM);
    // 10. FC2 (BM64: 640 blocks) -> bf16
    gemm64_bf16_kernel<3><<<dim3(HDIM/128, CAP/64, NEXP), 256, 0, stream>>>(
        fc1b, w2t, nullptr, fc2b, HDIM, FDIM,
        (long)CAP*FDIM, (long)FDIM*HDIM, (long)CAP*HDIM);
    // 11. combine (bf16 fc2)
    combine_kernel<<<S_LEN, 256, 0, stream>>>(h1, fc2b, dsts, expp, out);
}